// Round 14
// baseline (106.784 us; speedup 1.0000x reference)
//
#include <hip/hip_runtime.h>
#include <hip/hip_bf16.h>
#include <math.h>

#define Bsz 2
#define Lsz 1024
#define Dsz 1024
#define Hsz 16
#define Dh 64
#define Mtot (Bsz*Lsz)   // 2048
#define NC (Lsz/64)      // 16 chunks per (b,h)
#define LPAD 72          // LDS row pitch (bf16): 144B = 9*16B

typedef __bf16 bf16_t;
typedef bf16_t bf16x8 __attribute__((ext_vector_type(8)));
typedef bf16_t bf16x4 __attribute__((ext_vector_type(4)));
typedef float f32x4v __attribute__((ext_vector_type(4)));

__device__ __forceinline__ void gload16(const void* g, void* l) {
    __builtin_amdgcn_global_load_lds(
        (const __attribute__((address_space(1))) unsigned int*)g,
        (__attribute__((address_space(3))) unsigned int*)l, 16, 0, 0);
}

// ---------------- bf16 MFMA GEMM, 3-buffer 2-ahead pipeline, 1 barrier/step ----------------
// MODE 0: block tile 128x256, 4 waves of 64x128. acc[4][8]=128 VGPR + ~80 operand/addr
//         regs needs ~210 VGPR -> __launch_bounds__(256,2) pins 2 waves/SIMD so the
//         allocator gets a 256-VGPR budget (round-13's default heuristic chose 140 and
//         SPILLED the accumulators -> 48us, MfmaUtil 12%). 72KB LDS -> 2 blk/CU.
// MODE 1: block tile 64x128, 4 waves of 32x64; final GEMM (256 blocks); f32 out.
// Pipeline: stage at step t targets buf[(t+2)%3]=buf[(t-1)%3], whose ds_reads were
// consumed by MFMAs (lgkm-drained) before the end-of-step-(t-1) barrier.
// XCD mapping: blockIdx.x%8 = XCD; each XCD owns a contiguous block region.
template<int MODE>
__global__ __launch_bounds__(256, 2) void bgemm_kernel(
    const bf16_t* __restrict__ A, const bf16_t* __restrict__ Bt,
    const float* b0, const float* b1, const float* b2, const float* b3,
    bf16_t* Qo, bf16_t* q2o, bf16_t* Ko, bf16_t* Vo, bf16_t* k2o, float* Cout)
{
    constexpr int TM = (MODE == 0) ? 128 : 64;
    constexpr int TN = (MODE == 0) ? 256 : 128;
    constexpr int MF = (MODE == 0) ? 4 : 2;      // A frags per wave (wave M = MF*16)
    constexpr int NF = (MODE == 0) ? 8 : 4;      // B frags per wave (wave N = NF*16)

    __shared__ __align__(16) bf16_t As[3][TM * 32];
    __shared__ __align__(16) bf16_t Bs[3][TN * 32];
    const int tid  = threadIdx.x;
    const int lane = tid & 63;
    const int wid  = tid >> 6;

    const int lin = blockIdx.x;
    const int xcd = lin & 7;
    const int t0  = lin >> 3;
    int brow, bcolg;
    if (MODE == 0) {            // 2x4 XCD regions of 8x4 blocks (16 Mblk x 16 Nblk)
        brow  = (xcd & 1) * 8 + (t0 & 7);
        bcolg = (xcd >> 1) * 4 + (t0 >> 3);
    } else {                    // 4x2 XCD regions of 8x4 blocks (32 Mblk x 8 Nblk)
        brow  = (xcd & 3) * 8 + (t0 & 7);
        bcolg = (xcd >> 2) * 4 + (t0 >> 3);
    }
    const int row0  = brow * TM;
    const int col0g = bcolg * TN;
    const int p    = col0g >> 10;
    const int col0 = col0g & 1023;
    const int wr = (wid >> 1) * (MF * 16);
    const int wc = (wid & 1) * (NF * 16);

    const int srow = tid >> 2;
    const int scol = tid & 3;
    const int ssw  = (srow & 3) ^ ((srow >> 2) & 3);
    const int scol_sw = scol ^ ssw;
    const bf16_t* gA0 = A  + (size_t)(row0 + srow)        * 1024 + scol_sw * 8;
    const bf16_t* gA1 = A  + (size_t)(row0 + srow + 64)   * 1024 + scol_sw * 8;   // MODE0
    const bf16_t* gB0 = Bt + (size_t)(col0g + srow)       * 1024 + scol_sw * 8;
    const bf16_t* gB1 = Bt + (size_t)(col0g + srow + 64)  * 1024 + scol_sw * 8;
    const bf16_t* gB2 = Bt + (size_t)(col0g + srow + 128) * 1024 + scol_sw * 8;   // MODE0
    const bf16_t* gB3 = Bt + (size_t)(col0g + srow + 192) * 1024 + scol_sw * 8;   // MODE0

    const int laneRow = lane & 15;
    const int kblk = lane >> 4;
    const int swz = (kblk ^ (laneRow & 3) ^ ((laneRow >> 2) & 3)) & 3;
    const int aoff = (wr + laneRow) * 32 + swz * 8;
    const int boff = (wc + laneRow) * 32 + swz * 8;

    f32x4v acc[MF][NF];
    #pragma unroll
    for (int i = 0; i < MF; ++i)
        #pragma unroll
        for (int j = 0; j < NF; ++j)
            acc[i][j] = (f32x4v){0.f, 0.f, 0.f, 0.f};

    auto stage = [&](int buf) {
        gload16(gA0, &As[buf][tid * 8]);
        if (MODE == 0) gload16(gA1, &As[buf][(tid + 256) * 8]);
        gload16(gB0, &Bs[buf][tid * 8]);
        gload16(gB1, &Bs[buf][(tid + 256) * 8]);
        if (MODE == 0) {
            gload16(gB2, &Bs[buf][(tid + 512) * 8]);
            gload16(gB3, &Bs[buf][(tid + 768) * 8]);
        }
        gA0 += 32; gA1 += 32; gB0 += 32; gB1 += 32; gB2 += 32; gB3 += 32;
    };

    stage(0); stage(1);                                  // 2 stages in flight
    if (MODE == 0) { asm volatile("s_waitcnt vmcnt(6)" ::: "memory"); }
    else           { asm volatile("s_waitcnt vmcnt(3)" ::: "memory"); }
    __builtin_amdgcn_s_barrier();

    int cur = 0;
    for (int t = 0; t < 32; ++t) {
        bf16x8 af[MF], bfr[NF];
        #pragma unroll
        for (int f = 0; f < MF; ++f)
            af[f]  = *reinterpret_cast<const bf16x8*>(&As[cur][aoff + f * 512]);
        #pragma unroll
        for (int f = 0; f < NF; ++f)
            bfr[f] = *reinterpret_cast<const bf16x8*>(&Bs[cur][boff + f * 512]);
        if (t < 30) {
            int nxt = cur + 2; if (nxt >= 3) nxt -= 3;
            stage(nxt);                                  // buf last read at t-1: fenced
        }
        #pragma unroll
        for (int i = 0; i < MF; ++i)
            #pragma unroll
            for (int j = 0; j < NF; ++j)
                acc[i][j] = __builtin_amdgcn_mfma_f32_16x16x32_bf16(af[i], bfr[j], acc[i][j], 0, 0, 0);
        if (t < 30) {
            if (MODE == 0) { asm volatile("s_waitcnt vmcnt(6)" ::: "memory"); }
            else           { asm volatile("s_waitcnt vmcnt(3)" ::: "memory"); }
        } else if (t == 30) {
            asm volatile("s_waitcnt vmcnt(0)" ::: "memory");
        }
        if (t < 31) __builtin_amdgcn_s_barrier();
        cur = (cur == 2) ? 0 : cur + 1;
    }

    // epilogue: C/D layout col=lane&15, row=(lane>>4)*4+e
    const int crowb = row0 + wr + kblk * 4;
    const int ccolb = col0 + wc + laneRow;
    const float* bias = (MODE == 1) ? b0 : (p == 0) ? b0 : (p == 1) ? b1 : (p == 2) ? b2 : b3;
    float bv[NF];
    #pragma unroll
    for (int j = 0; j < NF; ++j) bv[j] = bias[ccolb + j * 16];
    #pragma unroll
    for (int i = 0; i < MF; ++i)
        #pragma unroll
        for (int j = 0; j < NF; ++j)
            #pragma unroll
            for (int e = 0; e < 4; ++e) {
                const float val = acc[i][j][e] + bv[j];
                const size_t idx = (size_t)(crowb + i * 16 + e) * 1024 + ccolb + j * 16;
                if (MODE == 1) {
                    Cout[idx] = val;
                } else if (p == 0) {
                    Qo[idx]  = (bf16_t)val;
                    q2o[idx] = (bf16_t)((val >= 0.f ? 0.02f * val : val) * 0.125f);
                } else if (p == 1) {
                    Ko[idx] = (bf16_t)val;
                } else if (p == 2) {
                    Vo[idx] = (bf16_t)val;
                } else {
                    k2o[idx] = (bf16_t)(1.f / (1.f + __expf(-val * 0.000625f)));
                }
            }
}

// ---------------- prep: 5x W transpose-cast (z<5) + x cast (z==5) ----------------
__global__ __launch_bounds__(256) void prep_kernel(
    const float* __restrict__ x, bf16_t* __restrict__ xb,
    const float* __restrict__ W0, const float* __restrict__ W1,
    const float* __restrict__ W2, const float* __restrict__ W3,
    const float* __restrict__ W4, bf16_t* __restrict__ Wt)
{
    const int z = blockIdx.z;
    const int tid = threadIdx.x;
    if (z == 5) {
        const int lin = blockIdx.y * 16 + blockIdx.x;
        #pragma unroll
        for (int u = 0; u < 8; ++u) {
            const size_t s = (size_t)lin * 2048 + u * 256 + tid;
            float4 v = *reinterpret_cast<const float4*>(&x[s * 4]);
            bf16x4 o;
            o[0] = (bf16_t)v.x; o[1] = (bf16_t)v.y; o[2] = (bf16_t)v.z; o[3] = (bf16_t)v.w;
            *reinterpret_cast<bf16x4*>(&xb[s * 4]) = o;
        }
        return;
    }
    const float* W = (z == 0) ? W0 : (z == 1) ? W1 : (z == 2) ? W2 : (z == 3) ? W3 : W4;
    bf16_t* T = Wt + (size_t)z * 1048576;

    __shared__ float Ls[64][65];
    const int k0 = blockIdx.x * 64;
    const int n0 = blockIdx.y * 64;
    const int r  = tid >> 4;
    const int c4 = (tid & 15) * 4;
    #pragma unroll
    for (int i = 0; i < 4; ++i) {
        float4 v = *reinterpret_cast<const float4*>(&W[(size_t)(k0 + r + i * 16) * Dsz + n0 + c4]);
        Ls[r + i * 16][c4 + 0] = v.x;
        Ls[r + i * 16][c4 + 1] = v.y;
        Ls[r + i * 16][c4 + 2] = v.z;
        Ls[r + i * 16][c4 + 3] = v.w;
    }
    __syncthreads();
    #pragma unroll
    for (int i = 0; i < 4; ++i) {
        const int n = r + i * 16;
        bf16x4 o;
        o[0] = (bf16_t)Ls[c4 + 0][n];
        o[1] = (bf16_t)Ls[c4 + 1][n];
        o[2] = (bf16_t)Ls[c4 + 2][n];
        o[3] = (bf16_t)Ls[c4 + 3][n];
        *reinterpret_cast<bf16x4*>(&T[(size_t)(n0 + n) * Dsz + k0 + c4]) = o;
    }
}

// ---------------- MFMA chunk intra (branch 1): P=Q.K^T (causal), dT1=V^T.K, Oi=P.V ----------------
__global__ __launch_bounds__(256) void chunk_intra_kernel(
    const bf16_t* __restrict__ Ap, const bf16_t* __restrict__ Kp,
    const bf16_t* __restrict__ Vp, bf16_t* __restrict__ Oi, bf16_t* __restrict__ dT)
{
    __shared__ __align__(16) bf16_t sQ[64 * LPAD];
    __shared__ __align__(16) bf16_t sK[64 * LPAD];
    __shared__ __align__(16) bf16_t sKt[64 * LPAD];
    __shared__ __align__(16) bf16_t sVt[64 * LPAD];
    __shared__ __align__(16) bf16_t sP[64 * LPAD];

    const int bid = blockIdx.x;
    const int c  = bid & (NC - 1);
    const int bh = bid >> 4;
    const int b = bh >> 4, h = bh & 15;
    const int tid = threadIdx.x;
    const size_t gbase = ((size_t)b * Lsz + (size_t)c * 64) * Dsz + h * Dh;

    #pragma unroll
    for (int cc = tid; cc < 512; cc += 256) {
        const int j = cc >> 3;
        const int d0 = (cc & 7) * 8;
        const size_t g = gbase + (size_t)j * 1024 + d0;
        bf16x8 qv = *reinterpret_cast<const bf16x8*>(&Ap[g]);
        bf16x8 kv = *reinterpret_cast<const bf16x8*>(&Kp[g]);
        bf16x8 vv = *reinterpret_cast<const bf16x8*>(&Vp[g]);
        *reinterpret_cast<bf16x8*>(&sQ[j * LPAD + d0]) = qv;
        *reinterpret_cast<bf16x8*>(&sK[j * LPAD + d0]) = kv;
        #pragma unroll
        for (int i = 0; i < 8; ++i) {
            sKt[(d0 + i) * LPAD + j] = kv[i];
            sVt[(d0 + i) * LPAD + j] = vv[i];
        }
    }
    __syncthreads();

    const int w = tid >> 6;
    const int lane = tid & 63;
    const int lr = lane & 15;
    const int kb = lane >> 4;
    const int m0 = w * 16;

    f32x4v accp[4], acct[4];
    #pragma unroll
    for (int n = 0; n < 4; ++n) { accp[n] = (f32x4v){0,0,0,0}; acct[n] = (f32x4v){0,0,0,0}; }
    #pragma unroll
    for (int kk = 0; kk < 2; ++kk) {
        const int c0 = kk * 32 + kb * 8;
        bf16x8 aq = *reinterpret_cast<const bf16x8*>(&sQ [(m0 + lr) * LPAD + c0]);
        bf16x8 av = *reinterpret_cast<const bf16x8*>(&sVt[(m0 + lr) * LPAD + c0]);
        #pragma unroll
        for (int n = 0; n < 4; ++n) {
            bf16x8 bk = *reinterpret_cast<const bf16x8*>(&sK [(n * 16 + lr) * LPAD + c0]);
            bf16x8 bt = *reinterpret_cast<const bf16x8*>(&sKt[(n * 16 + lr) * LPAD + c0]);
            accp[n] = __builtin_amdgcn_mfma_f32_16x16x32_bf16(aq, bk, accp[n], 0, 0, 0);
            acct[n] = __builtin_amdgcn_mfma_f32_16x16x32_bf16(av, bt, acct[n], 0, 0, 0);
        }
    }

    const size_t tbase = (size_t)bid * 4096;
    #pragma unroll
    for (int n = 0; n < 4; ++n)
        #pragma unroll
        for (int e = 0; e < 4; ++e) {
            const int r = m0 + kb * 4 + e;
            const int col = n * 16 + lr;
            dT[tbase + (size_t)r * 64 + col] = (bf16_t)acct[n][e];
            sP[r * LPAD + col] = (bf16_t)((col <= r) ? accp[n][e] : 0.f);
        }
    __syncthreads();

    f32x4v acco[4];
    #pragma unroll
    for (int n = 0; n < 4; ++n) acco[n] = (f32x4v){0,0,0,0};
    #pragma unroll
    for (int kk = 0; kk < 2; ++kk) {
        const int c0 = kk * 32 + kb * 8;
        bf16x8 a = *reinterpret_cast<const bf16x8*>(&sP[(m0 + lr) * LPAD + c0]);
        #pragma unroll
        for (int n = 0; n < 4; ++n) {
            bf16x8 bb = *reinterpret_cast<const bf16x8*>(&sVt[(n * 16 + lr) * LPAD + c0]);
            acco[n] = __builtin_amdgcn_mfma_f32_16x16x32_bf16(a, bb, acco[n], 0, 0, 0);
        }
    }
    #pragma unroll
    for (int n = 0; n < 4; ++n)
        #pragma unroll
        for (int e = 0; e < 4; ++e)
            Oi[gbase + (size_t)(m0 + kb * 4 + e) * 1024 + n * 16 + lr] = (bf16_t)acco[n][e];
}

// ---------------- fused inter1 + intra2 (O1 bf16) ----------------
__global__ __launch_bounds__(256) void inter1_intra2_kernel(
    const bf16_t* __restrict__ Qr, const bf16_t* __restrict__ q2p,
    const bf16_t* __restrict__ k2p, const bf16_t* __restrict__ dT1,
    const bf16_t* __restrict__ Oi1, const float* __restrict__ x,
    bf16_t* __restrict__ O1g, bf16_t* __restrict__ dT2, bf16_t* __restrict__ Oi2)
{
    __shared__ __align__(16) bf16_t sQ  [64 * LPAD];
    __shared__ __align__(16) bf16_t sq2 [64 * LPAD];
    __shared__ __align__(16) bf16_t sK2 [64 * LPAD];
    __shared__ __align__(16) bf16_t sk2t[64 * LPAD];
    __shared__ __align__(16) bf16_t sEt [64 * LPAD];
    __shared__ __align__(16) bf16_t sP  [64 * LPAD];
    __shared__ __align__(16) bf16_t sT  [64 * LPAD];

    const int bid = blockIdx.x;
    const int c  = bid & (NC - 1);
    const int bh = bid >> 4;
    const int b = bh >> 4, h = bh & 15;
    const int tid = threadIdx.x;
    const size_t gbase = ((size_t)b * Lsz + (size_t)c * 64) * Dsz + h * Dh;

    #pragma unroll
    for (int it = 0; it < 2; ++it) {
        const int cc = tid + it * 256;
        const int j = cc >> 3;
        const int d0 = (cc & 7) * 8;
        const size_t g = gbase + (size_t)j * 1024 + d0;
        bf16x8 qv  = *reinterpret_cast<const bf16x8*>(&Qr[g]);
        bf16x8 q2v = *reinterpret_cast<const bf16x8*>(&q2p[g]);
        bf16x8 k2v = *reinterpret_cast<const bf16x8*>(&k2p[g]);
        *reinterpret_cast<bf16x8*>(&sQ [j * LPAD + d0]) = qv;
        *reinterpret_cast<bf16x8*>(&sq2[j * LPAD + d0]) = q2v;
        *reinterpret_cast<bf16x8*>(&sK2[j * LPAD + d0]) = k2v;
        #pragma unroll
        for (int i = 0; i < 8; ++i)
            sk2t[(d0 + i) * LPAD + j] = k2v[i];
    }
    {   // exclusive prefix of dT1 over chunks -> sT (S1^T bf16), f32 accumulate
        const bf16_t* tb = dT1 + (size_t)bh * NC * 4096 + tid * 16;
        float acc[16];
        #pragma unroll
        for (int k = 0; k < 16; ++k) acc[k] = 0.f;
        for (int cc = 0; cc < c; ++cc) {
            bf16x8 v0 = *reinterpret_cast<const bf16x8*>(&tb[(size_t)cc * 4096]);
            bf16x8 v1 = *reinterpret_cast<const bf16x8*>(&tb[(size_t)cc * 4096 + 8]);
            #pragma unroll
            for (int k = 0; k < 8; ++k) { acc[k] += (float)v0[k]; acc[8 + k] += (float)v1[k]; }
        }
        const int row = tid >> 2;
        const int c16 = (tid & 3) * 16;
        bf16x8 o0, o1v;
        #pragma unroll
        for (int k = 0; k < 8; ++k) { o0[k] = (bf16_t)acc[k]; o1v[k] = (bf16_t)acc[8 + k]; }
        *reinterpret_cast<bf16x8*>(&sT[row * LPAD + c16]) = o0;
        *reinterpret_cast<bf16x8*>(&sT[row * LPAD + c16 + 8]) = o1v;
    }
    __syncthreads();

    const int w = tid >> 6;
    const int lane = tid & 63;
    const int lr = lane & 15;
    const int kb = lane >> 4;
    const int m0 = w * 16;

    f32x4v acci[4], accp[4];
    #pragma unroll
    for (int n = 0; n < 4; ++n) { acci[n] = (f32x4v){0,0,0,0}; accp[n] = (f32x4v){0,0,0,0}; }
    #pragma unroll
    for (int kk = 0; kk < 2; ++kk) {
        const int c0 = kk * 32 + kb * 8;
        bf16x8 aq  = *reinterpret_cast<const bf16x8*>(&sQ [(m0 + lr) * LPAD + c0]);
        bf16x8 aq2 = *reinterpret_cast<const bf16x8*>(&sq2[(m0 + lr) * LPAD + c0]);
        #pragma unroll
        for (int n = 0; n < 4; ++n) {
            bf16x8 bs = *reinterpret_cast<const bf16x8*>(&sT [(n * 16 + lr) * LPAD + c0]);
            bf16x8 bk = *reinterpret_cast<const bf16x8*>(&sK2[(n * 16 + lr) * LPAD + c0]);
            acci[n] = __builtin_amdgcn_mfma_f32_16x16x32_bf16(aq,  bs, acci[n], 0, 0, 0);
            accp[n] = __builtin_amdgcn_mfma_f32_16x16x32_bf16(aq2, bk, accp[n], 0, 0, 0);
        }
    }
    #pragma unroll
    for (int n = 0; n < 4; ++n)
        #pragma unroll
        for (int e = 0; e < 4; ++e) {
            const int iLoc = m0 + kb * 4 + e;
            const int col = n * 16 + lr;
            const int lg = c * 64 + iLoc;
            const size_t idx = gbase + (size_t)iLoc * 1024 + col;
            const float o1 = acci[n][e] + (float)Oi1[idx];
            O1g[idx] = (bf16_t)o1;
            const float ev = (lg < Lsz - 1) ? (x[idx + 1024] - o1) : 0.f;
            sEt[col * LPAD + iLoc] = (bf16_t)ev;
            sP[iLoc * LPAD + col] = (bf16_t)((col <= iLoc) ? accp[n][e] : 0.f);
        }
    __syncthreads();

    f32x4v acct[4], oi2[4];
    #pragma unroll
    for (int n = 0; n < 4; ++n) { acct[n] = (f32x4v){0,0,0,0}; oi2[n] = (f32x4v){0,0,0,0}; }
    #pragma unroll
    for (int kk = 0; kk < 2; ++kk) {
        const int c0 = kk * 32 + kb * 8;
        bf16x8 ae = *reinterpret_cast<const bf16x8*>(&sEt[(m0 + lr) * LPAD + c0]);
        bf16x8 ap = *reinterpret_cast<const bf16x8*>(&sP [(m0 + lr) * LPAD + c0]);
        #pragma unroll
        for (int n = 0; n < 4; ++n) {
            bf16x8 bt = *reinterpret_cast<const bf16x8*>(&sk2t[(n * 16 + lr) * LPAD + c0]);
            bf16x8 be = *reinterpret_cast<const bf16x8*>(&sEt [(n * 16 + lr) * LPAD + c0]);
            acct[n] = __builtin_amdgcn_mfma_f32_16x16x32_bf16(ae, bt, acct[n], 0, 0, 0);
            oi2[n]  = __builtin_amdgcn_mfma_f32_16x16x32_bf16(ap, be, oi2[n],  0, 0, 0);
        }
    }
    const size_t tbase = (size_t)bid * 4096;
    #pragma unroll
    for (int n = 0; n < 4; ++n)
        #pragma unroll
        for (int e = 0; e < 4; ++e) {
            const int r = m0 + kb * 4 + e;
            const int col = n * 16 + lr;
            dT2[tbase + (size_t)r * 64 + col] = (bf16_t)acct[n][e];
            Oi2[gbase + (size_t)r * 1024 + col] = (bf16_t)oi2[n][e];
        }
}

// ---------------- inter2: O2 = q2@S2 + Oi2; yb[l+1] = bf16(O1[l+1]+O2[l]) ----------------
__global__ __launch_bounds__(256) void inter2_kernel(
    const bf16_t* __restrict__ Ap, const bf16_t* __restrict__ dT,
    const bf16_t* __restrict__ Oi, const bf16_t* __restrict__ o1in,
    bf16_t* __restrict__ yb)
{
    __shared__ __align__(16) bf16_t sA[64 * LPAD];
    __shared__ __align__(16) bf16_t sT[64 * LPAD];

    const int bid = blockIdx.x;
    const int c  = bid & (NC - 1);
    const int bh = bid >> 4;
    const int b = bh >> 4, h = bh & 15;
    const int tid = threadIdx.x;
    const size_t gbase = ((size_t)b * Lsz + (size_t)c * 64) * Dsz + h * Dh;

    #pragma unroll
    for (int cc = tid; cc < 512; cc += 256) {
        const int j = cc >> 3;
        const int d0 = (cc & 7) * 8;
        bf16x8 av = *reinterpret_cast<const bf16x8*>(&Ap[gbase + (size_t)j * 1024 + d0]);
        *reinterpret_cast<bf16x8*>(&sA[j * LPAD + d0]) = av;
    }
    {
        const bf16_t* tb = dT + (size_t)bh * NC * 4096 + tid * 16;
        float acc[16];
        #pragma unroll
        for (int k = 0; k < 16; ++k) acc[k] = 0.f;
        for (int cc = 0; cc < c; ++cc) {
            bf16x8 v0 = *reinterpret_cast<const bf16x8*>(&tb[(size_t)cc * 4096]);
            bf16x8 v1 = *reinterpret_cast<const bf16x8*>(&tb[(size_t)cc * 4096 + 8]);
            #pragma unroll
            for (int k = 0; k < 8; ++k) { acc[k] += (float)v0[k]; acc[8 + k] += (float)v1[k]; }
        }
        const int row = tid >> 2;
        const int c16 = (tid & 3) * 16;
        bf16x8 o0, o1v;
        #pragma unroll
        for (int k = 0; k < 8; ++k) { o0[k] = (bf16_t)acc[k]; o1v[k] = (bf16_t)acc[8 + k]; }
        *reinterpret_cast<bf16x8*>(&sT[row * LPAD + c16]) = o0;
        *reinterpret_cast<bf16x8*>(&sT[row * LPAD + c16 + 8]) = o1v;
    }
    __syncthreads();

    const int w = tid >> 6;
    const int lane = tid & 63;
    const int lr = lane & 15;
    const int kb = lane >> 4;
    const int m0 = w * 16;

    f32x4v acc[4];
    #pragma unroll
    for (int n = 0; n < 4; ++n) acc[n] = (f32x4v){0,0,0,0};
    #pragma unroll
    for (int kk = 0; kk < 2; ++kk) {
        const int c0 = kk * 32 + kb * 8;
        bf16x8 a = *reinterpret_cast<const bf16x8*>(&sA[(m0 + lr) * LPAD + c0]);
        #pragma unroll
        for (int n = 0; n < 4; ++n) {
            bf16x8 bb = *reinterpret_cast<const bf16x8*>(&sT[(n * 16 + lr) * LPAD + c0]);
            acc[n] = __builtin_amdgcn_mfma_f32_16x16x32_bf16(a, bb, acc[n], 0, 0, 0);
        }
    }

    #pragma unroll
    for (int n = 0; n < 4; ++n)
        #pragma unroll
        for (int e = 0; e < 4; ++e) {
            const int iLoc = m0 + kb * 4 + e;
            const int lg = c * 64 + iLoc;
            const size_t idx = gbase + (size_t)iLoc * 1024 + n * 16 + lr;
            const float o2 = acc[n][e] + (float)Oi[idx];
            if (lg < Lsz - 1) yb[idx + 1024] = (bf16_t)((float)o1in[idx + 1024] + o2);
            if (lg == 0)      yb[idx] = o1in[idx];
        }
}

extern "C" void kernel_launch(void* const* d_in, const int* in_sizes, int n_in,
                              void* d_out, int out_size, void* d_ws, size_t ws_size,
                              hipStream_t stream) {
    const float* x   = (const float*)d_in[0];
    const float* Wq  = (const float*)d_in[1];
    const float* bq  = (const float*)d_in[2];
    const float* Wk1 = (const float*)d_in[3];
    const float* bk1 = (const float*)d_in[4];
    const float* Wv  = (const float*)d_in[5];
    const float* bv  = (const float*)d_in[6];
    const float* Wk2 = (const float*)d_in[7];
    const float* bk2 = (const float*)d_in[8];
    const float* Wp  = (const float*)d_in[9];
    const float* bp  = (const float*)d_in[10];
    float* out = (float*)d_out;
    float* ws  = (float*)d_ws;

    const size_t mat = (size_t)Mtot * Dsz;     // 2M elements
    bf16_t* O1  = (bf16_t*)ws;                  // bf16               [0, 1M)
    bf16_t* Oib = (bf16_t*)(ws + 2 * mat);      // bf16               [2M, 3M)
    bf16_t* dT1 = (bf16_t*)(ws + 3 * mat);      // bf16               [3M, 4M)
    bf16_t* dT2 = (bf16_t*)(ws + 4 * mat);      // bf16               [4M, 5M)
    bf16_t* xb  = (bf16_t*)(ws + 5 * mat);      // bf16               [5M, 6M)
    bf16_t* Wt  = (bf16_t*)(ws + 6 * mat);      // bf16 5M            [6M, 8.5M)
    float*  bb  = ws + 8 * mat + mat / 2;       // 8.5M
    bf16_t* Qr  = (bf16_t*)(bb);                // [8.5M, 9.5M)
    bf16_t* q2  = (bf16_t*)(bb + mat / 2);      // [9.5M, 10.5M)
    bf16_t* Kb  = (bf16_t*)(bb + mat);          // [10.5M, 11.5M)
    bf16_t* Vb  = (bf16_t*)(bb + 3 * mat / 2);  // [11.5M, 12.5M)
    bf16_t* k2  = (bf16_t*)(bb + 2 * mat);      // [12.5M, 13.5M)
    bf16_t* yb  = Qr;                           // Qr dead after inter1_intra2

    dim3 block(256);

    prep_kernel<<<dim3(16, 16, 6), block, 0, stream>>>(x, xb, Wq, Wk1, Wv, Wk2, Wp, Wt);

    bgemm_kernel<0><<<dim3(256), block, 0, stream>>>(
        xb, Wt, bq, bk1, bv, bk2, Qr, q2, Kb, Vb, k2, nullptr);

    chunk_intra_kernel<<<dim3(512), block, 0, stream>>>(Qr, Kb, Vb, Oib, dT1);
    inter1_intra2_kernel<<<dim3(512), block, 0, stream>>>(Qr, q2, k2, dT1, Oib, x, O1, dT2, Oib);
    inter2_kernel<<<dim3(512), block, 0, stream>>>(q2, dT2, Oib, O1, yb);

    bgemm_kernel<1><<<dim3(256), block, 0, stream>>>(
        yb, Wt + 4 * 1048576, bp, nullptr, nullptr, nullptr,
        nullptr, nullptr, nullptr, nullptr, nullptr, out);
}

// Round 15
// 91.870 us; speedup vs baseline: 1.1623x; 1.1623x over previous
//
#include <hip/hip_runtime.h>
#include <hip/hip_bf16.h>
#include <math.h>

#define Bsz 2
#define Lsz 1024
#define Dsz 1024
#define Hsz 16
#define Dh 64
#define Mtot (Bsz*Lsz)   // 2048
#define NC (Lsz/64)      // 16 chunks per (b,h)
#define LPAD 72          // LDS row pitch (bf16): 144B = 9*16B

typedef __bf16 bf16_t;
typedef bf16_t bf16x8 __attribute__((ext_vector_type(8)));
typedef bf16_t bf16x4 __attribute__((ext_vector_type(4)));
typedef float f32x4v __attribute__((ext_vector_type(4)));

__device__ __forceinline__ void gload16(const void* g, void* l) {
    __builtin_amdgcn_global_load_lds(
        (const __attribute__((address_space(1))) unsigned int*)g,
        (__attribute__((address_space(3))) unsigned int*)l, 16, 0, 0);
}

// ---------------- bf16 MFMA GEMM, 3-buffer 2-ahead pipeline, 1 barrier/step ----------------
// MODE 0: block tile 128x256 with *512 threads* = 8 waves (2M x 4N of 64x64 each).
//         256 blocks -> 1 block/CU -> 2 waves/SIMD (round-14's 256-thread version had
//         1 wave/SIMD: every ds_read/vmcnt/barrier stall fully exposed -> 48us, 12% MfmaUtil).
//         Per-thread stage = 3 gload16 (1 A chunk + 2 B chunks). 72KB LDS.
// MODE 1: block tile 64x128, 256 threads, 4 waves of 32x64; final GEMM; f32 out.
// Pipeline: stage at step t targets buf[(t+2)%3]=buf[(t-1)%3], whose ds_reads were
// consumed (lgkm-drained) before the end-of-step-(t-1) barrier. vmcnt(3) = older
// stage's 3 loads complete -> next tile resident. Never vmcnt(0) in steady state.
// XCD mapping: blockIdx.x%8 = XCD; each XCD owns a contiguous 4MB-working-set region.
template<int MODE>
__global__ __launch_bounds__((MODE == 0) ? 512 : 256, 2) void bgemm_kernel(
    const bf16_t* __restrict__ A, const bf16_t* __restrict__ Bt,
    const float* b0, const float* b1, const float* b2, const float* b3,
    bf16_t* Qo, bf16_t* q2o, bf16_t* Ko, bf16_t* Vo, bf16_t* k2o, float* Cout)
{
    constexpr int TM = (MODE == 0) ? 128 : 64;
    constexpr int TN = (MODE == 0) ? 256 : 128;
    constexpr int MF = (MODE == 0) ? 4 : 2;      // A frags per wave
    constexpr int NF = 4;                        // B frags per wave

    __shared__ __align__(16) bf16_t As[3][TM * 32];
    __shared__ __align__(16) bf16_t Bs[3][TN * 32];
    const int tid  = threadIdx.x;
    const int lane = tid & 63;
    const int wid  = tid >> 6;

    const int lin = blockIdx.x;
    const int xcd = lin & 7;
    const int t0  = lin >> 3;
    int brow, bcolg;
    if (MODE == 0) {            // 2x4 XCD regions of 8x4 blocks (16 Mblk x 16 Nblk)
        brow  = (xcd & 1) * 8 + (t0 & 7);
        bcolg = (xcd >> 1) * 4 + (t0 >> 3);
    } else {                    // 4x2 XCD regions of 8x4 blocks (32 Mblk x 8 Nblk)
        brow  = (xcd & 3) * 8 + (t0 & 7);
        bcolg = (xcd >> 2) * 4 + (t0 >> 3);
    }
    const int row0  = brow * TM;
    const int col0g = bcolg * TN;
    const int p    = col0g >> 10;
    const int col0 = col0g & 1023;
    const int wr = (MODE == 0) ? (wid >> 2) * 64 : (wid >> 1) * 32;
    const int wc = (MODE == 0) ? (wid & 3) * 64 : (wid & 1) * 64;

    const int srow = tid >> 2;                   // MODE0: 0..127, MODE1: 0..63
    const int scol = tid & 3;
    const int ssw  = (srow & 3) ^ ((srow >> 2) & 3);
    const int scol_sw = scol ^ ssw;
    // B-row offsets for the thread's 2nd B chunk: +TM (ssw invariant under +64/+128)
    const bf16_t* gA0 = A  + (size_t)(row0 + srow)        * 1024 + scol_sw * 8;
    const bf16_t* gB0 = Bt + (size_t)(col0g + srow)       * 1024 + scol_sw * 8;
    const bf16_t* gB1 = Bt + (size_t)(col0g + TM + srow)  * 1024 + scol_sw * 8;

    const int laneRow = lane & 15;
    const int kblk = lane >> 4;
    const int swz = (kblk ^ (laneRow & 3) ^ ((laneRow >> 2) & 3)) & 3;
    const int aoff = (wr + laneRow) * 32 + swz * 8;
    const int boff = (wc + laneRow) * 32 + swz * 8;

    constexpr int TPB = (MODE == 0) ? 512 : 256;

    f32x4v acc[MF][NF];
    #pragma unroll
    for (int i = 0; i < MF; ++i)
        #pragma unroll
        for (int j = 0; j < NF; ++j)
            acc[i][j] = (f32x4v){0.f, 0.f, 0.f, 0.f};

    auto stage = [&](int buf) {
        gload16(gA0, &As[buf][tid * 8]);
        gload16(gB0, &Bs[buf][tid * 8]);
        gload16(gB1, &Bs[buf][(tid + TPB) * 8]);
        gA0 += 32; gB0 += 32; gB1 += 32;
    };

    stage(0); stage(1);                                  // 6 loads in flight
    asm volatile("s_waitcnt vmcnt(3)" ::: "memory");     // tile 0 resident
    __builtin_amdgcn_s_barrier();

    int cur = 0;
    for (int t = 0; t < 32; ++t) {
        bf16x8 af[MF], bfr[NF];
        #pragma unroll
        for (int f = 0; f < MF; ++f)
            af[f]  = *reinterpret_cast<const bf16x8*>(&As[cur][aoff + f * 512]);
        #pragma unroll
        for (int f = 0; f < NF; ++f)
            bfr[f] = *reinterpret_cast<const bf16x8*>(&Bs[cur][boff + f * 512]);
        if (t < 30) {
            int nxt = cur + 2; if (nxt >= 3) nxt -= 3;
            stage(nxt);                                  // buf last read at t-1: fenced
        }
        #pragma unroll
        for (int i = 0; i < MF; ++i)
            #pragma unroll
            for (int j = 0; j < NF; ++j)
                acc[i][j] = __builtin_amdgcn_mfma_f32_16x16x32_bf16(af[i], bfr[j], acc[i][j], 0, 0, 0);
        if (t < 30)       { asm volatile("s_waitcnt vmcnt(3)" ::: "memory"); }
        else if (t == 30) { asm volatile("s_waitcnt vmcnt(0)" ::: "memory"); }
        if (t < 31) __builtin_amdgcn_s_barrier();
        cur = (cur == 2) ? 0 : cur + 1;
    }

    // epilogue: C/D layout col=lane&15, row=(lane>>4)*4+e
    const int crowb = row0 + wr + kblk * 4;
    const int ccolb = col0 + wc + laneRow;
    const float* bias = (MODE == 1) ? b0 : (p == 0) ? b0 : (p == 1) ? b1 : (p == 2) ? b2 : b3;
    float bv[NF];
    #pragma unroll
    for (int j = 0; j < NF; ++j) bv[j] = bias[ccolb + j * 16];
    #pragma unroll
    for (int i = 0; i < MF; ++i)
        #pragma unroll
        for (int j = 0; j < NF; ++j)
            #pragma unroll
            for (int e = 0; e < 4; ++e) {
                const float val = acc[i][j][e] + bv[j];
                const size_t idx = (size_t)(crowb + i * 16 + e) * 1024 + ccolb + j * 16;
                if (MODE == 1) {
                    Cout[idx] = val;
                } else if (p == 0) {
                    Qo[idx]  = (bf16_t)val;
                    q2o[idx] = (bf16_t)((val >= 0.f ? 0.02f * val : val) * 0.125f);
                } else if (p == 1) {
                    Ko[idx] = (bf16_t)val;
                } else if (p == 2) {
                    Vo[idx] = (bf16_t)val;
                } else {
                    k2o[idx] = (bf16_t)(1.f / (1.f + __expf(-val * 0.000625f)));
                }
            }
}

// ---------------- prep: 5x W transpose-cast (z<5) + x cast (z==5) ----------------
__global__ __launch_bounds__(256) void prep_kernel(
    const float* __restrict__ x, bf16_t* __restrict__ xb,
    const float* __restrict__ W0, const float* __restrict__ W1,
    const float* __restrict__ W2, const float* __restrict__ W3,
    const float* __restrict__ W4, bf16_t* __restrict__ Wt)
{
    const int z = blockIdx.z;
    const int tid = threadIdx.x;
    if (z == 5) {
        const int lin = blockIdx.y * 16 + blockIdx.x;
        #pragma unroll
        for (int u = 0; u < 8; ++u) {
            const size_t s = (size_t)lin * 2048 + u * 256 + tid;
            float4 v = *reinterpret_cast<const float4*>(&x[s * 4]);
            bf16x4 o;
            o[0] = (bf16_t)v.x; o[1] = (bf16_t)v.y; o[2] = (bf16_t)v.z; o[3] = (bf16_t)v.w;
            *reinterpret_cast<bf16x4*>(&xb[s * 4]) = o;
        }
        return;
    }
    const float* W = (z == 0) ? W0 : (z == 1) ? W1 : (z == 2) ? W2 : (z == 3) ? W3 : W4;
    bf16_t* T = Wt + (size_t)z * 1048576;

    __shared__ float Ls[64][65];
    const int k0 = blockIdx.x * 64;
    const int n0 = blockIdx.y * 64;
    const int r  = tid >> 4;
    const int c4 = (tid & 15) * 4;
    #pragma unroll
    for (int i = 0; i < 4; ++i) {
        float4 v = *reinterpret_cast<const float4*>(&W[(size_t)(k0 + r + i * 16) * Dsz + n0 + c4]);
        Ls[r + i * 16][c4 + 0] = v.x;
        Ls[r + i * 16][c4 + 1] = v.y;
        Ls[r + i * 16][c4 + 2] = v.z;
        Ls[r + i * 16][c4 + 3] = v.w;
    }
    __syncthreads();
    #pragma unroll
    for (int i = 0; i < 4; ++i) {
        const int n = r + i * 16;
        bf16x4 o;
        o[0] = (bf16_t)Ls[c4 + 0][n];
        o[1] = (bf16_t)Ls[c4 + 1][n];
        o[2] = (bf16_t)Ls[c4 + 2][n];
        o[3] = (bf16_t)Ls[c4 + 3][n];
        *reinterpret_cast<bf16x4*>(&T[(size_t)(n0 + n) * Dsz + k0 + c4]) = o;
    }
}

// ---------------- MFMA chunk intra (branch 1): P=Q.K^T (causal), dT1=V^T.K, Oi=P.V ----------------
__global__ __launch_bounds__(256) void chunk_intra_kernel(
    const bf16_t* __restrict__ Ap, const bf16_t* __restrict__ Kp,
    const bf16_t* __restrict__ Vp, bf16_t* __restrict__ Oi, bf16_t* __restrict__ dT)
{
    __shared__ __align__(16) bf16_t sQ[64 * LPAD];
    __shared__ __align__(16) bf16_t sK[64 * LPAD];
    __shared__ __align__(16) bf16_t sKt[64 * LPAD];
    __shared__ __align__(16) bf16_t sVt[64 * LPAD];
    __shared__ __align__(16) bf16_t sP[64 * LPAD];

    const int bid = blockIdx.x;
    const int c  = bid & (NC - 1);
    const int bh = bid >> 4;
    const int b = bh >> 4, h = bh & 15;
    const int tid = threadIdx.x;
    const size_t gbase = ((size_t)b * Lsz + (size_t)c * 64) * Dsz + h * Dh;

    #pragma unroll
    for (int cc = tid; cc < 512; cc += 256) {
        const int j = cc >> 3;
        const int d0 = (cc & 7) * 8;
        const size_t g = gbase + (size_t)j * 1024 + d0;
        bf16x8 qv = *reinterpret_cast<const bf16x8*>(&Ap[g]);
        bf16x8 kv = *reinterpret_cast<const bf16x8*>(&Kp[g]);
        bf16x8 vv = *reinterpret_cast<const bf16x8*>(&Vp[g]);
        *reinterpret_cast<bf16x8*>(&sQ[j * LPAD + d0]) = qv;
        *reinterpret_cast<bf16x8*>(&sK[j * LPAD + d0]) = kv;
        #pragma unroll
        for (int i = 0; i < 8; ++i) {
            sKt[(d0 + i) * LPAD + j] = kv[i];
            sVt[(d0 + i) * LPAD + j] = vv[i];
        }
    }
    __syncthreads();

    const int w = tid >> 6;
    const int lane = tid & 63;
    const int lr = lane & 15;
    const int kb = lane >> 4;
    const int m0 = w * 16;

    f32x4v accp[4], acct[4];
    #pragma unroll
    for (int n = 0; n < 4; ++n) { accp[n] = (f32x4v){0,0,0,0}; acct[n] = (f32x4v){0,0,0,0}; }
    #pragma unroll
    for (int kk = 0; kk < 2; ++kk) {
        const int c0 = kk * 32 + kb * 8;
        bf16x8 aq = *reinterpret_cast<const bf16x8*>(&sQ [(m0 + lr) * LPAD + c0]);
        bf16x8 av = *reinterpret_cast<const bf16x8*>(&sVt[(m0 + lr) * LPAD + c0]);
        #pragma unroll
        for (int n = 0; n < 4; ++n) {
            bf16x8 bk = *reinterpret_cast<const bf16x8*>(&sK [(n * 16 + lr) * LPAD + c0]);
            bf16x8 bt = *reinterpret_cast<const bf16x8*>(&sKt[(n * 16 + lr) * LPAD + c0]);
            accp[n] = __builtin_amdgcn_mfma_f32_16x16x32_bf16(aq, bk, accp[n], 0, 0, 0);
            acct[n] = __builtin_amdgcn_mfma_f32_16x16x32_bf16(av, bt, acct[n], 0, 0, 0);
        }
    }

    const size_t tbase = (size_t)bid * 4096;
    #pragma unroll
    for (int n = 0; n < 4; ++n)
        #pragma unroll
        for (int e = 0; e < 4; ++e) {
            const int r = m0 + kb * 4 + e;
            const int col = n * 16 + lr;
            dT[tbase + (size_t)r * 64 + col] = (bf16_t)acct[n][e];
            sP[r * LPAD + col] = (bf16_t)((col <= r) ? accp[n][e] : 0.f);
        }
    __syncthreads();

    f32x4v acco[4];
    #pragma unroll
    for (int n = 0; n < 4; ++n) acco[n] = (f32x4v){0,0,0,0};
    #pragma unroll
    for (int kk = 0; kk < 2; ++kk) {
        const int c0 = kk * 32 + kb * 8;
        bf16x8 a = *reinterpret_cast<const bf16x8*>(&sP[(m0 + lr) * LPAD + c0]);
        #pragma unroll
        for (int n = 0; n < 4; ++n) {
            bf16x8 bb = *reinterpret_cast<const bf16x8*>(&sVt[(n * 16 + lr) * LPAD + c0]);
            acco[n] = __builtin_amdgcn_mfma_f32_16x16x32_bf16(a, bb, acco[n], 0, 0, 0);
        }
    }
    #pragma unroll
    for (int n = 0; n < 4; ++n)
        #pragma unroll
        for (int e = 0; e < 4; ++e)
            Oi[gbase + (size_t)(m0 + kb * 4 + e) * 1024 + n * 16 + lr] = (bf16_t)acco[n][e];
}

// ---------------- fused inter1 + intra2 (O1 bf16) ----------------
__global__ __launch_bounds__(256) void inter1_intra2_kernel(
    const bf16_t* __restrict__ Qr, const bf16_t* __restrict__ q2p,
    const bf16_t* __restrict__ k2p, const bf16_t* __restrict__ dT1,
    const bf16_t* __restrict__ Oi1, const float* __restrict__ x,
    bf16_t* __restrict__ O1g, bf16_t* __restrict__ dT2, bf16_t* __restrict__ Oi2)
{
    __shared__ __align__(16) bf16_t sQ  [64 * LPAD];
    __shared__ __align__(16) bf16_t sq2 [64 * LPAD];
    __shared__ __align__(16) bf16_t sK2 [64 * LPAD];
    __shared__ __align__(16) bf16_t sk2t[64 * LPAD];
    __shared__ __align__(16) bf16_t sEt [64 * LPAD];
    __shared__ __align__(16) bf16_t sP  [64 * LPAD];
    __shared__ __align__(16) bf16_t sT  [64 * LPAD];

    const int bid = blockIdx.x;
    const int c  = bid & (NC - 1);
    const int bh = bid >> 4;
    const int b = bh >> 4, h = bh & 15;
    const int tid = threadIdx.x;
    const size_t gbase = ((size_t)b * Lsz + (size_t)c * 64) * Dsz + h * Dh;

    #pragma unroll
    for (int it = 0; it < 2; ++it) {
        const int cc = tid + it * 256;
        const int j = cc >> 3;
        const int d0 = (cc & 7) * 8;
        const size_t g = gbase + (size_t)j * 1024 + d0;
        bf16x8 qv  = *reinterpret_cast<const bf16x8*>(&Qr[g]);
        bf16x8 q2v = *reinterpret_cast<const bf16x8*>(&q2p[g]);
        bf16x8 k2v = *reinterpret_cast<const bf16x8*>(&k2p[g]);
        *reinterpret_cast<bf16x8*>(&sQ [j * LPAD + d0]) = qv;
        *reinterpret_cast<bf16x8*>(&sq2[j * LPAD + d0]) = q2v;
        *reinterpret_cast<bf16x8*>(&sK2[j * LPAD + d0]) = k2v;
        #pragma unroll
        for (int i = 0; i < 8; ++i)
            sk2t[(d0 + i) * LPAD + j] = k2v[i];
    }
    {   // exclusive prefix of dT1 over chunks -> sT (S1^T bf16), f32 accumulate
        const bf16_t* tb = dT1 + (size_t)bh * NC * 4096 + tid * 16;
        float acc[16];
        #pragma unroll
        for (int k = 0; k < 16; ++k) acc[k] = 0.f;
        for (int cc = 0; cc < c; ++cc) {
            bf16x8 v0 = *reinterpret_cast<const bf16x8*>(&tb[(size_t)cc * 4096]);
            bf16x8 v1 = *reinterpret_cast<const bf16x8*>(&tb[(size_t)cc * 4096 + 8]);
            #pragma unroll
            for (int k = 0; k < 8; ++k) { acc[k] += (float)v0[k]; acc[8 + k] += (float)v1[k]; }
        }
        const int row = tid >> 2;
        const int c16 = (tid & 3) * 16;
        bf16x8 o0, o1v;
        #pragma unroll
        for (int k = 0; k < 8; ++k) { o0[k] = (bf16_t)acc[k]; o1v[k] = (bf16_t)acc[8 + k]; }
        *reinterpret_cast<bf16x8*>(&sT[row * LPAD + c16]) = o0;
        *reinterpret_cast<bf16x8*>(&sT[row * LPAD + c16 + 8]) = o1v;
    }
    __syncthreads();

    const int w = tid >> 6;
    const int lane = tid & 63;
    const int lr = lane & 15;
    const int kb = lane >> 4;
    const int m0 = w * 16;

    f32x4v acci[4], accp[4];
    #pragma unroll
    for (int n = 0; n < 4; ++n) { acci[n] = (f32x4v){0,0,0,0}; accp[n] = (f32x4v){0,0,0,0}; }
    #pragma unroll
    for (int kk = 0; kk < 2; ++kk) {
        const int c0 = kk * 32 + kb * 8;
        bf16x8 aq  = *reinterpret_cast<const bf16x8*>(&sQ [(m0 + lr) * LPAD + c0]);
        bf16x8 aq2 = *reinterpret_cast<const bf16x8*>(&sq2[(m0 + lr) * LPAD + c0]);
        #pragma unroll
        for (int n = 0; n < 4; ++n) {
            bf16x8 bs = *reinterpret_cast<const bf16x8*>(&sT [(n * 16 + lr) * LPAD + c0]);
            bf16x8 bk = *reinterpret_cast<const bf16x8*>(&sK2[(n * 16 + lr) * LPAD + c0]);
            acci[n] = __builtin_amdgcn_mfma_f32_16x16x32_bf16(aq,  bs, acci[n], 0, 0, 0);
            accp[n] = __builtin_amdgcn_mfma_f32_16x16x32_bf16(aq2, bk, accp[n], 0, 0, 0);
        }
    }
    #pragma unroll
    for (int n = 0; n < 4; ++n)
        #pragma unroll
        for (int e = 0; e < 4; ++e) {
            const int iLoc = m0 + kb * 4 + e;
            const int col = n * 16 + lr;
            const int lg = c * 64 + iLoc;
            const size_t idx = gbase + (size_t)iLoc * 1024 + col;
            const float o1 = acci[n][e] + (float)Oi1[idx];
            O1g[idx] = (bf16_t)o1;
            const float ev = (lg < Lsz - 1) ? (x[idx + 1024] - o1) : 0.f;
            sEt[col * LPAD + iLoc] = (bf16_t)ev;
            sP[iLoc * LPAD + col] = (bf16_t)((col <= iLoc) ? accp[n][e] : 0.f);
        }
    __syncthreads();

    f32x4v acct[4], oi2[4];
    #pragma unroll
    for (int n = 0; n < 4; ++n) { acct[n] = (f32x4v){0,0,0,0}; oi2[n] = (f32x4v){0,0,0,0}; }
    #pragma unroll
    for (int kk = 0; kk < 2; ++kk) {
        const int c0 = kk * 32 + kb * 8;
        bf16x8 ae = *reinterpret_cast<const bf16x8*>(&sEt[(m0 + lr) * LPAD + c0]);
        bf16x8 ap = *reinterpret_cast<const bf16x8*>(&sP [(m0 + lr) * LPAD + c0]);
        #pragma unroll
        for (int n = 0; n < 4; ++n) {
            bf16x8 bt = *reinterpret_cast<const bf16x8*>(&sk2t[(n * 16 + lr) * LPAD + c0]);
            bf16x8 be = *reinterpret_cast<const bf16x8*>(&sEt [(n * 16 + lr) * LPAD + c0]);
            acct[n] = __builtin_amdgcn_mfma_f32_16x16x32_bf16(ae, bt, acct[n], 0, 0, 0);
            oi2[n]  = __builtin_amdgcn_mfma_f32_16x16x32_bf16(ap, be, oi2[n],  0, 0, 0);
        }
    }
    const size_t tbase = (size_t)bid * 4096;
    #pragma unroll
    for (int n = 0; n < 4; ++n)
        #pragma unroll
        for (int e = 0; e < 4; ++e) {
            const int r = m0 + kb * 4 + e;
            const int col = n * 16 + lr;
            dT2[tbase + (size_t)r * 64 + col] = (bf16_t)acct[n][e];
            Oi2[gbase + (size_t)r * 1024 + col] = (bf16_t)oi2[n][e];
        }
}

// ---------------- inter2: O2 = q2@S2 + Oi2; yb[l+1] = bf16(O1[l+1]+O2[l]) ----------------
__global__ __launch_bounds__(256) void inter2_kernel(
    const bf16_t* __restrict__ Ap, const bf16_t* __restrict__ dT,
    const bf16_t* __restrict__ Oi, const bf16_t* __restrict__ o1in,
    bf16_t* __restrict__ yb)
{
    __shared__ __align__(16) bf16_t sA[64 * LPAD];
    __shared__ __align__(16) bf16_t sT[64 * LPAD];

    const int bid = blockIdx.x;
    const int c  = bid & (NC - 1);
    const int bh = bid >> 4;
    const int b = bh >> 4, h = bh & 15;
    const int tid = threadIdx.x;
    const size_t gbase = ((size_t)b * Lsz + (size_t)c * 64) * Dsz + h * Dh;

    #pragma unroll
    for (int cc = tid; cc < 512; cc += 256) {
        const int j = cc >> 3;
        const int d0 = (cc & 7) * 8;
        bf16x8 av = *reinterpret_cast<const bf16x8*>(&Ap[gbase + (size_t)j * 1024 + d0]);
        *reinterpret_cast<bf16x8*>(&sA[j * LPAD + d0]) = av;
    }
    {
        const bf16_t* tb = dT + (size_t)bh * NC * 4096 + tid * 16;
        float acc[16];
        #pragma unroll
        for (int k = 0; k < 16; ++k) acc[k] = 0.f;
        for (int cc = 0; cc < c; ++cc) {
            bf16x8 v0 = *reinterpret_cast<const bf16x8*>(&tb[(size_t)cc * 4096]);
            bf16x8 v1 = *reinterpret_cast<const bf16x8*>(&tb[(size_t)cc * 4096 + 8]);
            #pragma unroll
            for (int k = 0; k < 8; ++k) { acc[k] += (float)v0[k]; acc[8 + k] += (float)v1[k]; }
        }
        const int row = tid >> 2;
        const int c16 = (tid & 3) * 16;
        bf16x8 o0, o1v;
        #pragma unroll
        for (int k = 0; k < 8; ++k) { o0[k] = (bf16_t)acc[k]; o1v[k] = (bf16_t)acc[8 + k]; }
        *reinterpret_cast<bf16x8*>(&sT[row * LPAD + c16]) = o0;
        *reinterpret_cast<bf16x8*>(&sT[row * LPAD + c16 + 8]) = o1v;
    }
    __syncthreads();

    const int w = tid >> 6;
    const int lane = tid & 63;
    const int lr = lane & 15;
    const int kb = lane >> 4;
    const int m0 = w * 16;

    f32x4v acc[4];
    #pragma unroll
    for (int n = 0; n < 4; ++n) acc[n] = (f32x4v){0,0,0,0};
    #pragma unroll
    for (int kk = 0; kk < 2; ++kk) {
        const int c0 = kk * 32 + kb * 8;
        bf16x8 a = *reinterpret_cast<const bf16x8*>(&sA[(m0 + lr) * LPAD + c0]);
        #pragma unroll
        for (int n = 0; n < 4; ++n) {
            bf16x8 bb = *reinterpret_cast<const bf16x8*>(&sT[(n * 16 + lr) * LPAD + c0]);
            acc[n] = __builtin_amdgcn_mfma_f32_16x16x32_bf16(a, bb, acc[n], 0, 0, 0);
        }
    }

    #pragma unroll
    for (int n = 0; n < 4; ++n)
        #pragma unroll
        for (int e = 0; e < 4; ++e) {
            const int iLoc = m0 + kb * 4 + e;
            const int lg = c * 64 + iLoc;
            const size_t idx = gbase + (size_t)iLoc * 1024 + n * 16 + lr;
            const float o2 = acc[n][e] + (float)Oi[idx];
            if (lg < Lsz - 1) yb[idx + 1024] = (bf16_t)((float)o1in[idx + 1024] + o2);
            if (lg == 0)      yb[idx] = o1in[idx];
        }
}

extern "C" void kernel_launch(void* const* d_in, const int* in_sizes, int n_in,
                              void* d_out, int out_size, void* d_ws, size_t ws_size,
                              hipStream_t stream) {
    const float* x   = (const float*)d_in[0];
    const float* Wq  = (const float*)d_in[1];
    const float* bq  = (const float*)d_in[2];
    const float* Wk1 = (const float*)d_in[3];
    const float* bk1 = (const float*)d_in[4];
    const float* Wv  = (const float*)d_in[5];
    const float* bv  = (const float*)d_in[6];
    const float* Wk2 = (const float*)d_in[7];
    const float* bk2 = (const float*)d_in[8];
    const float* Wp  = (const float*)d_in[9];
    const float* bp  = (const float*)d_in[10];
    float* out = (float*)d_out;
    float* ws  = (float*)d_ws;

    const size_t mat = (size_t)Mtot * Dsz;     // 2M elements
    bf16_t* O1  = (bf16_t*)ws;                  // bf16               [0, 1M)
    bf16_t* Oib = (bf16_t*)(ws + 2 * mat);      // bf16               [2M, 3M)
    bf16_t* dT1 = (bf16_t*)(ws + 3 * mat);      // bf16               [3M, 4M)
    bf16_t* dT2 = (bf16_t*)(ws + 4 * mat);      // bf16               [4M, 5M)
    bf16_t* xb  = (bf16_t*)(ws + 5 * mat);      // bf16               [5M, 6M)
    bf16_t* Wt  = (bf16_t*)(ws + 6 * mat);      // bf16 5M            [6M, 8.5M)
    float*  bb  = ws + 8 * mat + mat / 2;       // 8.5M
    bf16_t* Qr  = (bf16_t*)(bb);                // [8.5M, 9.5M)
    bf16_t* q2  = (bf16_t*)(bb + mat / 2);      // [9.5M, 10.5M)
    bf16_t* Kb  = (bf16_t*)(bb + mat);          // [10.5M, 11.5M)
    bf16_t* Vb  = (bf16_t*)(bb + 3 * mat / 2);  // [11.5M, 12.5M)
    bf16_t* k2  = (bf16_t*)(bb + 2 * mat);      // [12.5M, 13.5M)
    bf16_t* yb  = Qr;                           // Qr dead after inter1_intra2

    dim3 block(256);

    prep_kernel<<<dim3(16, 16, 6), block, 0, stream>>>(x, xb, Wq, Wk1, Wv, Wk2, Wp, Wt);

    bgemm_kernel<0><<<dim3(256), dim3(512), 0, stream>>>(
        xb, Wt, bq, bk1, bv, bk2, Qr, q2, Kb, Vb, k2, nullptr);

    chunk_intra_kernel<<<dim3(512), block, 0, stream>>>(Qr, Kb, Vb, Oib, dT1);
    inter1_intra2_kernel<<<dim3(512), block, 0, stream>>>(Qr, q2, k2, dT1, Oib, x, O1, dT2, Oib);
    inter2_kernel<<<dim3(512), block, 0, stream>>>(q2, dT2, Oib, O1, yb);

    bgemm_kernel<1><<<dim3(256), block, 0, stream>>>(
        yb, Wt + 4 * 1048576, bp, nullptr, nullptr, nullptr,
        nullptr, nullptr, nullptr, nullptr, nullptr, out);
}

// Round 16
// 90.412 us; speedup vs baseline: 1.1811x; 1.0161x over previous
//
#include <hip/hip_runtime.h>
#include <hip/hip_bf16.h>
#include <math.h>

#define Bsz 2
#define Lsz 1024
#define Dsz 1024
#define Hsz 16
#define Dh 64
#define Mtot (Bsz*Lsz)   // 2048
#define NC (Lsz/64)      // 16 chunks per (b,h)
#define LPAD 72          // LDS row pitch (bf16): 144B = 9*16B

typedef __bf16 bf16_t;
typedef bf16_t bf16x8 __attribute__((ext_vector_type(8)));
typedef bf16_t bf16x4 __attribute__((ext_vector_type(4)));
typedef float f32x4v __attribute__((ext_vector_type(4)));

__device__ __forceinline__ void gload16(const void* g, void* l) {
    __builtin_amdgcn_global_load_lds(
        (const __attribute__((address_space(1))) unsigned int*)g,
        (__attribute__((address_space(3))) unsigned int*)l, 16, 0, 0);
}

// ---------------- bf16 MFMA GEMM, 3-buffer 2-ahead pipeline, 1 barrier/step ----------------
// MODE 0: block tile 128x256 with 512 threads = 8 waves (2M x 4N of 64x64 each).
//         256 blocks -> 1 block/CU -> 2 waves/SIMD. Per-thread stage = 3 gload16.
// MODE 1: block tile 64x128, 256 threads, 4 waves of 32x64; final GEMM; f32 out.
// Pipeline: stage at step t targets buf[(t+2)%3]=buf[(t-1)%3], whose ds_reads were
// consumed (lgkm-drained) before the end-of-step-(t-1) barrier. vmcnt(3) = older
// stage's 3 loads complete -> next tile resident. Never vmcnt(0) in steady state.
// XCD mapping: blockIdx.x%8 = XCD; each XCD owns a contiguous block region.
template<int MODE>
__global__ __launch_bounds__((MODE == 0) ? 512 : 256, 2) void bgemm_kernel(
    const bf16_t* __restrict__ A, const bf16_t* __restrict__ Bt,
    const float* b0, const float* b1, const float* b2, const float* b3,
    bf16_t* Qo, bf16_t* q2o, bf16_t* Ko, bf16_t* Vo, bf16_t* k2o, float* Cout)
{
    constexpr int TM = (MODE == 0) ? 128 : 64;
    constexpr int TN = (MODE == 0) ? 256 : 128;
    constexpr int MF = (MODE == 0) ? 4 : 2;      // A frags per wave
    constexpr int NF = 4;                        // B frags per wave

    __shared__ __align__(16) bf16_t As[3][TM * 32];
    __shared__ __align__(16) bf16_t Bs[3][TN * 32];
    const int tid  = threadIdx.x;
    const int lane = tid & 63;
    const int wid  = tid >> 6;

    const int lin = blockIdx.x;
    const int xcd = lin & 7;
    const int t0  = lin >> 3;
    int brow, bcolg;
    if (MODE == 0) {            // 2x4 XCD regions of 8x4 blocks (16 Mblk x 16 Nblk)
        brow  = (xcd & 1) * 8 + (t0 & 7);
        bcolg = (xcd >> 1) * 4 + (t0 >> 3);
    } else {                    // 4x2 XCD regions of 8x4 blocks (32 Mblk x 8 Nblk)
        brow  = (xcd & 3) * 8 + (t0 & 7);
        bcolg = (xcd >> 2) * 4 + (t0 >> 3);
    }
    const int row0  = brow * TM;
    const int col0g = bcolg * TN;
    const int p    = col0g >> 10;
    const int col0 = col0g & 1023;
    const int wr = (MODE == 0) ? (wid >> 2) * 64 : (wid >> 1) * 32;
    const int wc = (MODE == 0) ? (wid & 3) * 64 : (wid & 1) * 64;

    const int srow = tid >> 2;
    const int scol = tid & 3;
    const int ssw  = (srow & 3) ^ ((srow >> 2) & 3);
    const int scol_sw = scol ^ ssw;
    const bf16_t* gA0 = A  + (size_t)(row0 + srow)        * 1024 + scol_sw * 8;
    const bf16_t* gB0 = Bt + (size_t)(col0g + srow)       * 1024 + scol_sw * 8;
    const bf16_t* gB1 = Bt + (size_t)(col0g + TM + srow)  * 1024 + scol_sw * 8;

    const int laneRow = lane & 15;
    const int kblk = lane >> 4;
    const int swz = (kblk ^ (laneRow & 3) ^ ((laneRow >> 2) & 3)) & 3;
    const int aoff = (wr + laneRow) * 32 + swz * 8;
    const int boff = (wc + laneRow) * 32 + swz * 8;

    constexpr int TPB = (MODE == 0) ? 512 : 256;

    f32x4v acc[MF][NF];
    #pragma unroll
    for (int i = 0; i < MF; ++i)
        #pragma unroll
        for (int j = 0; j < NF; ++j)
            acc[i][j] = (f32x4v){0.f, 0.f, 0.f, 0.f};

    auto stage = [&](int buf) {
        gload16(gA0, &As[buf][tid * 8]);
        gload16(gB0, &Bs[buf][tid * 8]);
        gload16(gB1, &Bs[buf][(tid + TPB) * 8]);
        gA0 += 32; gB0 += 32; gB1 += 32;
    };

    stage(0); stage(1);                                  // 6 loads in flight
    asm volatile("s_waitcnt vmcnt(3)" ::: "memory");     // tile 0 resident
    __builtin_amdgcn_s_barrier();

    int cur = 0;
    for (int t = 0; t < 32; ++t) {
        bf16x8 af[MF], bfr[NF];
        #pragma unroll
        for (int f = 0; f < MF; ++f)
            af[f]  = *reinterpret_cast<const bf16x8*>(&As[cur][aoff + f * 512]);
        #pragma unroll
        for (int f = 0; f < NF; ++f)
            bfr[f] = *reinterpret_cast<const bf16x8*>(&Bs[cur][boff + f * 512]);
        if (t < 30) {
            int nxt = cur + 2; if (nxt >= 3) nxt -= 3;
            stage(nxt);                                  // buf last read at t-1: fenced
        }
        #pragma unroll
        for (int i = 0; i < MF; ++i)
            #pragma unroll
            for (int j = 0; j < NF; ++j)
                acc[i][j] = __builtin_amdgcn_mfma_f32_16x16x32_bf16(af[i], bfr[j], acc[i][j], 0, 0, 0);
        if (t < 30)       { asm volatile("s_waitcnt vmcnt(3)" ::: "memory"); }
        else if (t == 30) { asm volatile("s_waitcnt vmcnt(0)" ::: "memory"); }
        if (t < 31) __builtin_amdgcn_s_barrier();
        cur = (cur == 2) ? 0 : cur + 1;
    }

    // epilogue: C/D layout col=lane&15, row=(lane>>4)*4+e
    const int crowb = row0 + wr + kblk * 4;
    const int ccolb = col0 + wc + laneRow;
    const float* bias = (MODE == 1) ? b0 : (p == 0) ? b0 : (p == 1) ? b1 : (p == 2) ? b2 : b3;
    float bv[NF];
    #pragma unroll
    for (int j = 0; j < NF; ++j) bv[j] = bias[ccolb + j * 16];
    #pragma unroll
    for (int i = 0; i < MF; ++i)
        #pragma unroll
        for (int j = 0; j < NF; ++j)
            #pragma unroll
            for (int e = 0; e < 4; ++e) {
                const float val = acc[i][j][e] + bv[j];
                const size_t idx = (size_t)(crowb + i * 16 + e) * 1024 + ccolb + j * 16;
                if (MODE == 1) {
                    Cout[idx] = val;
                } else if (p == 0) {
                    Qo[idx]  = (bf16_t)val;
                    q2o[idx] = (bf16_t)((val >= 0.f ? 0.02f * val : val) * 0.125f);
                } else if (p == 1) {
                    Ko[idx] = (bf16_t)val;
                } else if (p == 2) {
                    Vo[idx] = (bf16_t)val;
                } else {
                    k2o[idx] = (bf16_t)(1.f / (1.f + __expf(-val * 0.000625f)));
                }
            }
}

// ---------------- prep: 5x W transpose-cast (z<5) + x cast (z==5) ----------------
__global__ __launch_bounds__(256) void prep_kernel(
    const float* __restrict__ x, bf16_t* __restrict__ xb,
    const float* __restrict__ W0, const float* __restrict__ W1,
    const float* __restrict__ W2, const float* __restrict__ W3,
    const float* __restrict__ W4, bf16_t* __restrict__ Wt)
{
    const int z = blockIdx.z;
    const int tid = threadIdx.x;
    if (z == 5) {
        const int lin = blockIdx.y * 16 + blockIdx.x;
        #pragma unroll
        for (int u = 0; u < 8; ++u) {
            const size_t s = (size_t)lin * 2048 + u * 256 + tid;
            float4 v = *reinterpret_cast<const float4*>(&x[s * 4]);
            bf16x4 o;
            o[0] = (bf16_t)v.x; o[1] = (bf16_t)v.y; o[2] = (bf16_t)v.z; o[3] = (bf16_t)v.w;
            *reinterpret_cast<bf16x4*>(&xb[s * 4]) = o;
        }
        return;
    }
    const float* W = (z == 0) ? W0 : (z == 1) ? W1 : (z == 2) ? W2 : (z == 3) ? W3 : W4;
    bf16_t* T = Wt + (size_t)z * 1048576;

    __shared__ float Ls[64][65];
    const int k0 = blockIdx.x * 64;
    const int n0 = blockIdx.y * 64;
    const int r  = tid >> 4;
    const int c4 = (tid & 15) * 4;
    #pragma unroll
    for (int i = 0; i < 4; ++i) {
        float4 v = *reinterpret_cast<const float4*>(&W[(size_t)(k0 + r + i * 16) * Dsz + n0 + c4]);
        Ls[r + i * 16][c4 + 0] = v.x;
        Ls[r + i * 16][c4 + 1] = v.y;
        Ls[r + i * 16][c4 + 2] = v.z;
        Ls[r + i * 16][c4 + 3] = v.w;
    }
    __syncthreads();
    #pragma unroll
    for (int i = 0; i < 4; ++i) {
        const int n = r + i * 16;
        bf16x4 o;
        o[0] = (bf16_t)Ls[c4 + 0][n];
        o[1] = (bf16_t)Ls[c4 + 1][n];
        o[2] = (bf16_t)Ls[c4 + 2][n];
        o[3] = (bf16_t)Ls[c4 + 3][n];
        *reinterpret_cast<bf16x4*>(&T[(size_t)(n0 + n) * Dsz + k0 + c4]) = o;
    }
}

// ---------------- MFMA chunk intra (branch 1): P=Q.K^T (causal), dT1=V^T.K, Oi=P.V ----------------
__global__ __launch_bounds__(256) void chunk_intra_kernel(
    const bf16_t* __restrict__ Ap, const bf16_t* __restrict__ Kp,
    const bf16_t* __restrict__ Vp, bf16_t* __restrict__ Oi, bf16_t* __restrict__ dT)
{
    __shared__ __align__(16) bf16_t sQ[64 * LPAD];
    __shared__ __align__(16) bf16_t sK[64 * LPAD];
    __shared__ __align__(16) bf16_t sKt[64 * LPAD];
    __shared__ __align__(16) bf16_t sVt[64 * LPAD];
    __shared__ __align__(16) bf16_t sP[64 * LPAD];

    const int bid = blockIdx.x;
    const int c  = bid & (NC - 1);
    const int bh = bid >> 4;
    const int b = bh >> 4, h = bh & 15;
    const int tid = threadIdx.x;
    const size_t gbase = ((size_t)b * Lsz + (size_t)c * 64) * Dsz + h * Dh;

    #pragma unroll
    for (int cc = tid; cc < 512; cc += 256) {
        const int j = cc >> 3;
        const int d0 = (cc & 7) * 8;
        const size_t g = gbase + (size_t)j * 1024 + d0;
        bf16x8 qv = *reinterpret_cast<const bf16x8*>(&Ap[g]);
        bf16x8 kv = *reinterpret_cast<const bf16x8*>(&Kp[g]);
        bf16x8 vv = *reinterpret_cast<const bf16x8*>(&Vp[g]);
        *reinterpret_cast<bf16x8*>(&sQ[j * LPAD + d0]) = qv;
        *reinterpret_cast<bf16x8*>(&sK[j * LPAD + d0]) = kv;
        #pragma unroll
        for (int i = 0; i < 8; ++i) {
            sKt[(d0 + i) * LPAD + j] = kv[i];
            sVt[(d0 + i) * LPAD + j] = vv[i];
        }
    }
    __syncthreads();

    const int w = tid >> 6;
    const int lane = tid & 63;
    const int lr = lane & 15;
    const int kb = lane >> 4;
    const int m0 = w * 16;

    f32x4v accp[4], acct[4];
    #pragma unroll
    for (int n = 0; n < 4; ++n) { accp[n] = (f32x4v){0,0,0,0}; acct[n] = (f32x4v){0,0,0,0}; }
    #pragma unroll
    for (int kk = 0; kk < 2; ++kk) {
        const int c0 = kk * 32 + kb * 8;
        bf16x8 aq = *reinterpret_cast<const bf16x8*>(&sQ [(m0 + lr) * LPAD + c0]);
        bf16x8 av = *reinterpret_cast<const bf16x8*>(&sVt[(m0 + lr) * LPAD + c0]);
        #pragma unroll
        for (int n = 0; n < 4; ++n) {
            bf16x8 bk = *reinterpret_cast<const bf16x8*>(&sK [(n * 16 + lr) * LPAD + c0]);
            bf16x8 bt = *reinterpret_cast<const bf16x8*>(&sKt[(n * 16 + lr) * LPAD + c0]);
            accp[n] = __builtin_amdgcn_mfma_f32_16x16x32_bf16(aq, bk, accp[n], 0, 0, 0);
            acct[n] = __builtin_amdgcn_mfma_f32_16x16x32_bf16(av, bt, acct[n], 0, 0, 0);
        }
    }

    const size_t tbase = (size_t)bid * 4096;
    #pragma unroll
    for (int n = 0; n < 4; ++n)
        #pragma unroll
        for (int e = 0; e < 4; ++e) {
            const int r = m0 + kb * 4 + e;
            const int col = n * 16 + lr;
            dT[tbase + (size_t)r * 64 + col] = (bf16_t)acct[n][e];
            sP[r * LPAD + col] = (bf16_t)((col <= r) ? accp[n][e] : 0.f);
        }
    __syncthreads();

    f32x4v acco[4];
    #pragma unroll
    for (int n = 0; n < 4; ++n) acco[n] = (f32x4v){0,0,0,0};
    #pragma unroll
    for (int kk = 0; kk < 2; ++kk) {
        const int c0 = kk * 32 + kb * 8;
        bf16x8 a = *reinterpret_cast<const bf16x8*>(&sP[(m0 + lr) * LPAD + c0]);
        #pragma unroll
        for (int n = 0; n < 4; ++n) {
            bf16x8 bb = *reinterpret_cast<const bf16x8*>(&sVt[(n * 16 + lr) * LPAD + c0]);
            acco[n] = __builtin_amdgcn_mfma_f32_16x16x32_bf16(a, bb, acco[n], 0, 0, 0);
        }
    }
    #pragma unroll
    for (int n = 0; n < 4; ++n)
        #pragma unroll
        for (int e = 0; e < 4; ++e)
            Oi[gbase + (size_t)(m0 + kb * 4 + e) * 1024 + n * 16 + lr] = (bf16_t)acco[n][e];
}

// ---------------- fused inter1 + intra2 (E from bf16 xb; read-only, no alias) ----------------
__global__ __launch_bounds__(256) void inter1_intra2_kernel(
    const bf16_t* __restrict__ Qr, const bf16_t* __restrict__ q2p,
    const bf16_t* __restrict__ k2p, const bf16_t* __restrict__ dT1,
    const bf16_t* __restrict__ Oi1, const bf16_t* __restrict__ xbin,
    bf16_t* __restrict__ O1g, bf16_t* __restrict__ dT2, bf16_t* __restrict__ Oi2)
{
    __shared__ __align__(16) bf16_t sQ  [64 * LPAD];
    __shared__ __align__(16) bf16_t sq2 [64 * LPAD];
    __shared__ __align__(16) bf16_t sK2 [64 * LPAD];
    __shared__ __align__(16) bf16_t sk2t[64 * LPAD];
    __shared__ __align__(16) bf16_t sEt [64 * LPAD];
    __shared__ __align__(16) bf16_t sP  [64 * LPAD];
    __shared__ __align__(16) bf16_t sT  [64 * LPAD];

    const int bid = blockIdx.x;
    const int c  = bid & (NC - 1);
    const int bh = bid >> 4;
    const int b = bh >> 4, h = bh & 15;
    const int tid = threadIdx.x;
    const size_t gbase = ((size_t)b * Lsz + (size_t)c * 64) * Dsz + h * Dh;

    #pragma unroll
    for (int it = 0; it < 2; ++it) {
        const int cc = tid + it * 256;
        const int j = cc >> 3;
        const int d0 = (cc & 7) * 8;
        const size_t g = gbase + (size_t)j * 1024 + d0;
        bf16x8 qv  = *reinterpret_cast<const bf16x8*>(&Qr[g]);
        bf16x8 q2v = *reinterpret_cast<const bf16x8*>(&q2p[g]);
        bf16x8 k2v = *reinterpret_cast<const bf16x8*>(&k2p[g]);
        *reinterpret_cast<bf16x8*>(&sQ [j * LPAD + d0]) = qv;
        *reinterpret_cast<bf16x8*>(&sq2[j * LPAD + d0]) = q2v;
        *reinterpret_cast<bf16x8*>(&sK2[j * LPAD + d0]) = k2v;
        #pragma unroll
        for (int i = 0; i < 8; ++i)
            sk2t[(d0 + i) * LPAD + j] = k2v[i];
    }
    {   // exclusive prefix of dT1 over chunks -> sT (S1^T bf16), f32 accumulate
        const bf16_t* tb = dT1 + (size_t)bh * NC * 4096 + tid * 16;
        float acc[16];
        #pragma unroll
        for (int k = 0; k < 16; ++k) acc[k] = 0.f;
        for (int cc = 0; cc < c; ++cc) {
            bf16x8 v0 = *reinterpret_cast<const bf16x8*>(&tb[(size_t)cc * 4096]);
            bf16x8 v1 = *reinterpret_cast<const bf16x8*>(&tb[(size_t)cc * 4096 + 8]);
            #pragma unroll
            for (int k = 0; k < 8; ++k) { acc[k] += (float)v0[k]; acc[8 + k] += (float)v1[k]; }
        }
        const int row = tid >> 2;
        const int c16 = (tid & 3) * 16;
        bf16x8 o0, o1v;
        #pragma unroll
        for (int k = 0; k < 8; ++k) { o0[k] = (bf16_t)acc[k]; o1v[k] = (bf16_t)acc[8 + k]; }
        *reinterpret_cast<bf16x8*>(&sT[row * LPAD + c16]) = o0;
        *reinterpret_cast<bf16x8*>(&sT[row * LPAD + c16 + 8]) = o1v;
    }
    __syncthreads();

    const int w = tid >> 6;
    const int lane = tid & 63;
    const int lr = lane & 15;
    const int kb = lane >> 4;
    const int m0 = w * 16;

    f32x4v acci[4], accp[4];
    #pragma unroll
    for (int n = 0; n < 4; ++n) { acci[n] = (f32x4v){0,0,0,0}; accp[n] = (f32x4v){0,0,0,0}; }
    #pragma unroll
    for (int kk = 0; kk < 2; ++kk) {
        const int c0 = kk * 32 + kb * 8;
        bf16x8 aq  = *reinterpret_cast<const bf16x8*>(&sQ [(m0 + lr) * LPAD + c0]);
        bf16x8 aq2 = *reinterpret_cast<const bf16x8*>(&sq2[(m0 + lr) * LPAD + c0]);
        #pragma unroll
        for (int n = 0; n < 4; ++n) {
            bf16x8 bs = *reinterpret_cast<const bf16x8*>(&sT [(n * 16 + lr) * LPAD + c0]);
            bf16x8 bk = *reinterpret_cast<const bf16x8*>(&sK2[(n * 16 + lr) * LPAD + c0]);
            acci[n] = __builtin_amdgcn_mfma_f32_16x16x32_bf16(aq,  bs, acci[n], 0, 0, 0);
            accp[n] = __builtin_amdgcn_mfma_f32_16x16x32_bf16(aq2, bk, accp[n], 0, 0, 0);
        }
    }
    #pragma unroll
    for (int n = 0; n < 4; ++n)
        #pragma unroll
        for (int e = 0; e < 4; ++e) {
            const int iLoc = m0 + kb * 4 + e;
            const int col = n * 16 + lr;
            const int lg = c * 64 + iLoc;
            const size_t idx = gbase + (size_t)iLoc * 1024 + col;
            const float o1 = acci[n][e] + (float)Oi1[idx];
            O1g[idx] = (bf16_t)o1;
            const float ev = (lg < Lsz - 1) ? ((float)xbin[idx + 1024] - o1) : 0.f;
            sEt[col * LPAD + iLoc] = (bf16_t)ev;
            sP[iLoc * LPAD + col] = (bf16_t)((col <= iLoc) ? accp[n][e] : 0.f);
        }
    __syncthreads();

    f32x4v acct[4], oi2[4];
    #pragma unroll
    for (int n = 0; n < 4; ++n) { acct[n] = (f32x4v){0,0,0,0}; oi2[n] = (f32x4v){0,0,0,0}; }
    #pragma unroll
    for (int kk = 0; kk < 2; ++kk) {
        const int c0 = kk * 32 + kb * 8;
        bf16x8 ae = *reinterpret_cast<const bf16x8*>(&sEt[(m0 + lr) * LPAD + c0]);
        bf16x8 ap = *reinterpret_cast<const bf16x8*>(&sP [(m0 + lr) * LPAD + c0]);
        #pragma unroll
        for (int n = 0; n < 4; ++n) {
            bf16x8 bt = *reinterpret_cast<const bf16x8*>(&sk2t[(n * 16 + lr) * LPAD + c0]);
            bf16x8 be = *reinterpret_cast<const bf16x8*>(&sEt [(n * 16 + lr) * LPAD + c0]);
            acct[n] = __builtin_amdgcn_mfma_f32_16x16x32_bf16(ae, bt, acct[n], 0, 0, 0);
            oi2[n]  = __builtin_amdgcn_mfma_f32_16x16x32_bf16(ap, be, oi2[n],  0, 0, 0);
        }
    }
    const size_t tbase = (size_t)bid * 4096;
    #pragma unroll
    for (int n = 0; n < 4; ++n)
        #pragma unroll
        for (int e = 0; e < 4; ++e) {
            const int r = m0 + kb * 4 + e;
            const int col = n * 16 + lr;
            dT2[tbase + (size_t)r * 64 + col] = (bf16_t)acct[n][e];
            Oi2[gbase + (size_t)r * 1024 + col] = (bf16_t)oi2[n][e];
        }
}

// ---------------- inter2: O2 = q2@S2 + Oi2; yb[l+1] = bf16(O1[l+1]+O2[l]) ----------------
__global__ __launch_bounds__(256) void inter2_kernel(
    const bf16_t* __restrict__ Ap, const bf16_t* __restrict__ dT,
    const bf16_t* __restrict__ Oi, const bf16_t* __restrict__ o1in,
    bf16_t* __restrict__ yb)
{
    __shared__ __align__(16) bf16_t sA[64 * LPAD];
    __shared__ __align__(16) bf16_t sT[64 * LPAD];

    const int bid = blockIdx.x;
    const int c  = bid & (NC - 1);
    const int bh = bid >> 4;
    const int b = bh >> 4, h = bh & 15;
    const int tid = threadIdx.x;
    const size_t gbase = ((size_t)b * Lsz + (size_t)c * 64) * Dsz + h * Dh;

    #pragma unroll
    for (int cc = tid; cc < 512; cc += 256) {
        const int j = cc >> 3;
        const int d0 = (cc & 7) * 8;
        bf16x8 av = *reinterpret_cast<const bf16x8*>(&Ap[gbase + (size_t)j * 1024 + d0]);
        *reinterpret_cast<bf16x8*>(&sA[j * LPAD + d0]) = av;
    }
    {
        const bf16_t* tb = dT + (size_t)bh * NC * 4096 + tid * 16;
        float acc[16];
        #pragma unroll
        for (int k = 0; k < 16; ++k) acc[k] = 0.f;
        for (int cc = 0; cc < c; ++cc) {
            bf16x8 v0 = *reinterpret_cast<const bf16x8*>(&tb[(size_t)cc * 4096]);
            bf16x8 v1 = *reinterpret_cast<const bf16x8*>(&tb[(size_t)cc * 4096 + 8]);
            #pragma unroll
            for (int k = 0; k < 8; ++k) { acc[k] += (float)v0[k]; acc[8 + k] += (float)v1[k]; }
        }
        const int row = tid >> 2;
        const int c16 = (tid & 3) * 16;
        bf16x8 o0, o1v;
        #pragma unroll
        for (int k = 0; k < 8; ++k) { o0[k] = (bf16_t)acc[k]; o1v[k] = (bf16_t)acc[8 + k]; }
        *reinterpret_cast<bf16x8*>(&sT[row * LPAD + c16]) = o0;
        *reinterpret_cast<bf16x8*>(&sT[row * LPAD + c16 + 8]) = o1v;
    }
    __syncthreads();

    const int w = tid >> 6;
    const int lane = tid & 63;
    const int lr = lane & 15;
    const int kb = lane >> 4;
    const int m0 = w * 16;

    f32x4v acc[4];
    #pragma unroll
    for (int n = 0; n < 4; ++n) acc[n] = (f32x4v){0,0,0,0};
    #pragma unroll
    for (int kk = 0; kk < 2; ++kk) {
        const int c0 = kk * 32 + kb * 8;
        bf16x8 a = *reinterpret_cast<const bf16x8*>(&sA[(m0 + lr) * LPAD + c0]);
        #pragma unroll
        for (int n = 0; n < 4; ++n) {
            bf16x8 bb = *reinterpret_cast<const bf16x8*>(&sT[(n * 16 + lr) * LPAD + c0]);
            acc[n] = __builtin_amdgcn_mfma_f32_16x16x32_bf16(a, bb, acc[n], 0, 0, 0);
        }
    }

    #pragma unroll
    for (int n = 0; n < 4; ++n)
        #pragma unroll
        for (int e = 0; e < 4; ++e) {
            const int iLoc = m0 + kb * 4 + e;
            const int lg = c * 64 + iLoc;
            const size_t idx = gbase + (size_t)iLoc * 1024 + n * 16 + lr;
            const float o2 = acc[n][e] + (float)Oi[idx];
            if (lg < Lsz - 1) yb[idx + 1024] = (bf16_t)((float)o1in[idx + 1024] + o2);
            if (lg == 0)      yb[idx] = o1in[idx];
        }
}

extern "C" void kernel_launch(void* const* d_in, const int* in_sizes, int n_in,
                              void* d_out, int out_size, void* d_ws, size_t ws_size,
                              hipStream_t stream) {
    const float* x   = (const float*)d_in[0];
    const float* Wq  = (const float*)d_in[1];
    const float* bq  = (const float*)d_in[2];
    const float* Wk1 = (const float*)d_in[3];
    const float* bk1 = (const float*)d_in[4];
    const float* Wv  = (const float*)d_in[5];
    const float* bv  = (const float*)d_in[6];
    const float* Wk2 = (const float*)d_in[7];
    const float* bk2 = (const float*)d_in[8];
    const float* Wp  = (const float*)d_in[9];
    const float* bp  = (const float*)d_in[10];
    float* out = (float*)d_out;
    float* ws  = (float*)d_ws;

    const size_t mat = (size_t)Mtot * Dsz;     // 2M elements
    bf16_t* O1  = (bf16_t*)ws;                  // bf16               [0, 1M)
    bf16_t* Oib = (bf16_t*)(ws + 2 * mat);      // bf16               [2M, 3M)
    bf16_t* dT1 = (bf16_t*)(ws + 3 * mat);      // bf16               [3M, 4M)
    bf16_t* dT2 = (bf16_t*)(ws + 4 * mat);      // bf16               [4M, 5M)
    bf16_t* xb  = (bf16_t*)(ws + 5 * mat);      // bf16               [5M, 6M)
    bf16_t* Wt  = (bf16_t*)(ws + 6 * mat);      // bf16 5M            [6M, 8.5M)
    float*  bb  = ws + 8 * mat + mat / 2;       // 8.5M
    bf16_t* Qr  = (bf16_t*)(bb);                // [8.5M, 9.5M)
    bf16_t* q2  = (bf16_t*)(bb + mat / 2);      // [9.5M, 10.5M)
    bf16_t* Kb  = (bf16_t*)(bb + mat);          // [10.5M, 11.5M)
    bf16_t* Vb  = (bf16_t*)(bb + 3 * mat / 2);  // [11.5M, 12.5M)
    bf16_t* k2  = (bf16_t*)(bb + 2 * mat);      // [12.5M, 13.5M)
    bf16_t* yb  = Qr;                           // Qr dead after inter1_intra2

    dim3 block(256);

    prep_kernel<<<dim3(16, 16, 6), block, 0, stream>>>(x, xb, Wq, Wk1, Wv, Wk2, Wp, Wt);

    bgemm_kernel<0><<<dim3(256), dim3(512), 0, stream>>>(
        xb, Wt, bq, bk1, bv, bk2, Qr, q2, Kb, Vb, k2, nullptr);

    chunk_intra_kernel<<<dim3(512), block, 0, stream>>>(Qr, Kb, Vb, Oib, dT1);
    inter1_intra2_kernel<<<dim3(512), block, 0, stream>>>(Qr, q2, k2, dT1, Oib, xb, O1, dT2, Oib);
    inter2_kernel<<<dim3(512), block, 0, stream>>>(q2, dT2, Oib, O1, yb);

    bgemm_kernel<1><<<dim3(256), block, 0, stream>>>(
        yb, Wt + 4 * 1048576, bp, nullptr, nullptr, nullptr,
        nullptr, nullptr, nullptr, nullptr, nullptr, out);
}

// Round 17
// 89.519 us; speedup vs baseline: 1.1929x; 1.0100x over previous
//
#include <hip/hip_runtime.h>
#include <hip/hip_bf16.h>
#include <math.h>

#define Bsz 2
#define Lsz 1024
#define Dsz 1024
#define Hsz 16
#define Dh 64
#define Mtot (Bsz*Lsz)   // 2048
#define NC (Lsz/64)      // 16 chunks per (b,h)
#define LPAD 72          // LDS row pitch (bf16): 144B = 9*16B

typedef __bf16 bf16_t;
typedef bf16_t bf16x8 __attribute__((ext_vector_type(8)));
typedef bf16_t bf16x4 __attribute__((ext_vector_type(4)));
typedef float f32x4v __attribute__((ext_vector_type(4)));

__device__ __forceinline__ void gload16(const void* g, void* l) {
    __builtin_amdgcn_global_load_lds(
        (const __attribute__((address_space(1))) unsigned int*)g,
        (__attribute__((address_space(3))) unsigned int*)l, 16, 0, 0);
}

// ---------------- bf16 MFMA GEMM, 3-buffer 2-ahead pipeline, 1 barrier/step ----------------
// MODE 0: block tile 128x256, 512 threads = 8 waves (2M x 4N of 64x64). 256 blocks ->
//         1 block/CU -> 2 waves/SIMD. Stage = 3 gload16/thread, vmcnt(3).
// MODE 1: block tile 64x64, 256 threads = 4 waves (2M x 2N of 32x32). 512 blocks ->
//         2 blocks/CU -> 2 waves/SIMD (the old 64x128/256-block config was 1 wave/SIMD:
//         round-14's geometry bug). Stage = 2 gload16/thread, vmcnt(2). f32 out + bias.
// Pipeline: stage at step t targets buf[(t+2)%3]=buf[(t-1)%3], whose ds_reads were
// consumed (lgkm-drained) before the end-of-step-(t-1) barrier. Never vmcnt(0) steady.
// XCD mapping: blockIdx.x%8 = XCD; each XCD owns a contiguous block region.
template<int MODE>
__global__ __launch_bounds__((MODE == 0) ? 512 : 256, 2) void bgemm_kernel(
    const bf16_t* __restrict__ A, const bf16_t* __restrict__ Bt,
    const float* b0, const float* b1, const float* b2, const float* b3,
    bf16_t* Qo, bf16_t* q2o, bf16_t* Ko, bf16_t* Vo, bf16_t* k2o, float* Cout)
{
    constexpr int TM = (MODE == 0) ? 128 : 64;
    constexpr int TN = (MODE == 0) ? 256 : 64;
    constexpr int MF = (MODE == 0) ? 4 : 2;      // A frags per wave
    constexpr int NF = (MODE == 0) ? 4 : 2;      // B frags per wave
    constexpr int TPB = (MODE == 0) ? 512 : 256;

    __shared__ __align__(16) bf16_t As[3][TM * 32];
    __shared__ __align__(16) bf16_t Bs[3][TN * 32];
    const int tid  = threadIdx.x;
    const int lane = tid & 63;
    const int wid  = tid >> 6;

    const int lin = blockIdx.x;
    const int xcd = lin & 7;
    const int t0  = lin >> 3;
    int brow, bcolg;
    if (MODE == 0) {            // 2x4 XCD regions of 8x4 blocks (16 Mblk x 16 Nblk)
        brow  = (xcd & 1) * 8 + (t0 & 7);
        bcolg = (xcd >> 1) * 4 + (t0 >> 3);
    } else {                    // 4x2 XCD regions of 8x8 blocks (32 Mblk x 16 Nblk)
        brow  = (xcd & 3) * 8 + (t0 & 7);
        bcolg = (xcd >> 2) * 8 + (t0 >> 3);
    }
    const int row0  = brow * TM;
    const int col0g = bcolg * TN;
    const int p    = col0g >> 10;
    const int col0 = col0g & 1023;
    const int wr = (MODE == 0) ? (wid >> 2) * 64 : (wid >> 1) * 32;
    const int wc = (MODE == 0) ? (wid & 3) * 64 : (wid & 1) * 32;

    const int srow = tid >> 2;                   // MODE0: 0..127, MODE1: 0..63
    const int scol = tid & 3;
    const int ssw  = (srow & 3) ^ ((srow >> 2) & 3);
    const int scol_sw = scol ^ ssw;
    const bf16_t* gA0 = A  + (size_t)(row0 + srow)        * 1024 + scol_sw * 8;
    const bf16_t* gB0 = Bt + (size_t)(col0g + srow)       * 1024 + scol_sw * 8;
    const bf16_t* gB1 = (MODE == 0)
        ? Bt + (size_t)(col0g + TM + srow) * 1024 + scol_sw * 8
        : nullptr;

    const int laneRow = lane & 15;
    const int kblk = lane >> 4;
    const int swz = (kblk ^ (laneRow & 3) ^ ((laneRow >> 2) & 3)) & 3;
    const int aoff = (wr + laneRow) * 32 + swz * 8;
    const int boff = (wc + laneRow) * 32 + swz * 8;

    f32x4v acc[MF][NF];
    #pragma unroll
    for (int i = 0; i < MF; ++i)
        #pragma unroll
        for (int j = 0; j < NF; ++j)
            acc[i][j] = (f32x4v){0.f, 0.f, 0.f, 0.f};

    auto stage = [&](int buf) {
        gload16(gA0, &As[buf][tid * 8]);
        gload16(gB0, &Bs[buf][tid * 8]);
        if (MODE == 0) {
            gload16(gB1, &Bs[buf][(tid + TPB) * 8]);
            gB1 += 32;
        }
        gA0 += 32; gB0 += 32;
    };

    stage(0); stage(1);                                  // 2 stages in flight
    if (MODE == 0) { asm volatile("s_waitcnt vmcnt(3)" ::: "memory"); }
    else           { asm volatile("s_waitcnt vmcnt(2)" ::: "memory"); }
    __builtin_amdgcn_s_barrier();

    int cur = 0;
    for (int t = 0; t < 32; ++t) {
        bf16x8 af[MF], bfr[NF];
        #pragma unroll
        for (int f = 0; f < MF; ++f)
            af[f]  = *reinterpret_cast<const bf16x8*>(&As[cur][aoff + f * 512]);
        #pragma unroll
        for (int f = 0; f < NF; ++f)
            bfr[f] = *reinterpret_cast<const bf16x8*>(&Bs[cur][boff + f * 512]);
        if (t < 30) {
            int nxt = cur + 2; if (nxt >= 3) nxt -= 3;
            stage(nxt);                                  // buf last read at t-1: fenced
        }
        #pragma unroll
        for (int i = 0; i < MF; ++i)
            #pragma unroll
            for (int j = 0; j < NF; ++j)
                acc[i][j] = __builtin_amdgcn_mfma_f32_16x16x32_bf16(af[i], bfr[j], acc[i][j], 0, 0, 0);
        if (t < 30) {
            if (MODE == 0) { asm volatile("s_waitcnt vmcnt(3)" ::: "memory"); }
            else           { asm volatile("s_waitcnt vmcnt(2)" ::: "memory"); }
        } else if (t == 30) {
            asm volatile("s_waitcnt vmcnt(0)" ::: "memory");
        }
        if (t < 31) __builtin_amdgcn_s_barrier();
        cur = (cur == 2) ? 0 : cur + 1;
    }

    // epilogue: C/D layout col=lane&15, row=(lane>>4)*4+e
    const int crowb = row0 + wr + kblk * 4;
    const int ccolb = col0 + wc + laneRow;
    const float* bias = (MODE == 1) ? b0 : (p == 0) ? b0 : (p == 1) ? b1 : (p == 2) ? b2 : b3;
    float bv[NF];
    #pragma unroll
    for (int j = 0; j < NF; ++j) bv[j] = bias[ccolb + j * 16];
    #pragma unroll
    for (int i = 0; i < MF; ++i)
        #pragma unroll
        for (int j = 0; j < NF; ++j)
            #pragma unroll
            for (int e = 0; e < 4; ++e) {
                const float val = acc[i][j][e] + bv[j];
                const size_t idx = (size_t)(crowb + i * 16 + e) * 1024 + ccolb + j * 16;
                if (MODE == 1) {
                    Cout[idx] = val;
                } else if (p == 0) {
                    Qo[idx]  = (bf16_t)val;
                    q2o[idx] = (bf16_t)((val >= 0.f ? 0.02f * val : val) * 0.125f);
                } else if (p == 1) {
                    Ko[idx] = (bf16_t)val;
                } else if (p == 2) {
                    Vo[idx] = (bf16_t)val;
                } else {
                    k2o[idx] = (bf16_t)(1.f / (1.f + __expf(-val * 0.000625f)));
                }
            }
}

// ---------------- prep: 5x W transpose-cast (z<5) + x cast (z==5) ----------------
__global__ __launch_bounds__(256) void prep_kernel(
    const float* __restrict__ x, bf16_t* __restrict__ xb,
    const float* __restrict__ W0, const float* __restrict__ W1,
    const float* __restrict__ W2, const float* __restrict__ W3,
    const float* __restrict__ W4, bf16_t* __restrict__ Wt)
{
    const int z = blockIdx.z;
    const int tid = threadIdx.x;
    if (z == 5) {
        const int lin = blockIdx.y * 16 + blockIdx.x;
        #pragma unroll
        for (int u = 0; u < 8; ++u) {
            const size_t s = (size_t)lin * 2048 + u * 256 + tid;
            float4 v = *reinterpret_cast<const float4*>(&x[s * 4]);
            bf16x4 o;
            o[0] = (bf16_t)v.x; o[1] = (bf16_t)v.y; o[2] = (bf16_t)v.z; o[3] = (bf16_t)v.w;
            *reinterpret_cast<bf16x4*>(&xb[s * 4]) = o;
        }
        return;
    }
    const float* W = (z == 0) ? W0 : (z == 1) ? W1 : (z == 2) ? W2 : (z == 3) ? W3 : W4;
    bf16_t* T = Wt + (size_t)z * 1048576;

    __shared__ float Ls[64][65];
    const int k0 = blockIdx.x * 64;
    const int n0 = blockIdx.y * 64;
    const int r  = tid >> 4;
    const int c4 = (tid & 15) * 4;
    #pragma unroll
    for (int i = 0; i < 4; ++i) {
        float4 v = *reinterpret_cast<const float4*>(&W[(size_t)(k0 + r + i * 16) * Dsz + n0 + c4]);
        Ls[r + i * 16][c4 + 0] = v.x;
        Ls[r + i * 16][c4 + 1] = v.y;
        Ls[r + i * 16][c4 + 2] = v.z;
        Ls[r + i * 16][c4 + 3] = v.w;
    }
    __syncthreads();
    #pragma unroll
    for (int i = 0; i < 4; ++i) {
        const int n = r + i * 16;
        bf16x4 o;
        o[0] = (bf16_t)Ls[c4 + 0][n];
        o[1] = (bf16_t)Ls[c4 + 1][n];
        o[2] = (bf16_t)Ls[c4 + 2][n];
        o[3] = (bf16_t)Ls[c4 + 3][n];
        *reinterpret_cast<bf16x4*>(&T[(size_t)(n0 + n) * Dsz + k0 + c4]) = o;
    }
}

// ---------------- MFMA chunk intra (branch 1): P=Q.K^T (causal), dT1=V^T.K, Oi=P.V ----------------
__global__ __launch_bounds__(256) void chunk_intra_kernel(
    const bf16_t* __restrict__ Ap, const bf16_t* __restrict__ Kp,
    const bf16_t* __restrict__ Vp, bf16_t* __restrict__ Oi, bf16_t* __restrict__ dT)
{
    __shared__ __align__(16) bf16_t sQ[64 * LPAD];
    __shared__ __align__(16) bf16_t sK[64 * LPAD];
    __shared__ __align__(16) bf16_t sKt[64 * LPAD];
    __shared__ __align__(16) bf16_t sVt[64 * LPAD];
    __shared__ __align__(16) bf16_t sP[64 * LPAD];

    const int bid = blockIdx.x;
    const int c  = bid & (NC - 1);
    const int bh = bid >> 4;
    const int b = bh >> 4, h = bh & 15;
    const int tid = threadIdx.x;
    const size_t gbase = ((size_t)b * Lsz + (size_t)c * 64) * Dsz + h * Dh;

    #pragma unroll
    for (int cc = tid; cc < 512; cc += 256) {
        const int j = cc >> 3;
        const int d0 = (cc & 7) * 8;
        const size_t g = gbase + (size_t)j * 1024 + d0;
        bf16x8 qv = *reinterpret_cast<const bf16x8*>(&Ap[g]);
        bf16x8 kv = *reinterpret_cast<const bf16x8*>(&Kp[g]);
        bf16x8 vv = *reinterpret_cast<const bf16x8*>(&Vp[g]);
        *reinterpret_cast<bf16x8*>(&sQ[j * LPAD + d0]) = qv;
        *reinterpret_cast<bf16x8*>(&sK[j * LPAD + d0]) = kv;
        #pragma unroll
        for (int i = 0; i < 8; ++i) {
            sKt[(d0 + i) * LPAD + j] = kv[i];
            sVt[(d0 + i) * LPAD + j] = vv[i];
        }
    }
    __syncthreads();

    const int w = tid >> 6;
    const int lane = tid & 63;
    const int lr = lane & 15;
    const int kb = lane >> 4;
    const int m0 = w * 16;

    f32x4v accp[4], acct[4];
    #pragma unroll
    for (int n = 0; n < 4; ++n) { accp[n] = (f32x4v){0,0,0,0}; acct[n] = (f32x4v){0,0,0,0}; }
    #pragma unroll
    for (int kk = 0; kk < 2; ++kk) {
        const int c0 = kk * 32 + kb * 8;
        bf16x8 aq = *reinterpret_cast<const bf16x8*>(&sQ [(m0 + lr) * LPAD + c0]);
        bf16x8 av = *reinterpret_cast<const bf16x8*>(&sVt[(m0 + lr) * LPAD + c0]);
        #pragma unroll
        for (int n = 0; n < 4; ++n) {
            bf16x8 bk = *reinterpret_cast<const bf16x8*>(&sK [(n * 16 + lr) * LPAD + c0]);
            bf16x8 bt = *reinterpret_cast<const bf16x8*>(&sKt[(n * 16 + lr) * LPAD + c0]);
            accp[n] = __builtin_amdgcn_mfma_f32_16x16x32_bf16(aq, bk, accp[n], 0, 0, 0);
            acct[n] = __builtin_amdgcn_mfma_f32_16x16x32_bf16(av, bt, acct[n], 0, 0, 0);
        }
    }

    const size_t tbase = (size_t)bid * 4096;
    #pragma unroll
    for (int n = 0; n < 4; ++n)
        #pragma unroll
        for (int e = 0; e < 4; ++e) {
            const int r = m0 + kb * 4 + e;
            const int col = n * 16 + lr;
            dT[tbase + (size_t)r * 64 + col] = (bf16_t)acct[n][e];
            sP[r * LPAD + col] = (bf16_t)((col <= r) ? accp[n][e] : 0.f);
        }
    __syncthreads();

    f32x4v acco[4];
    #pragma unroll
    for (int n = 0; n < 4; ++n) acco[n] = (f32x4v){0,0,0,0};
    #pragma unroll
    for (int kk = 0; kk < 2; ++kk) {
        const int c0 = kk * 32 + kb * 8;
        bf16x8 a = *reinterpret_cast<const bf16x8*>(&sP[(m0 + lr) * LPAD + c0]);
        #pragma unroll
        for (int n = 0; n < 4; ++n) {
            bf16x8 bb = *reinterpret_cast<const bf16x8*>(&sVt[(n * 16 + lr) * LPAD + c0]);
            acco[n] = __builtin_amdgcn_mfma_f32_16x16x32_bf16(a, bb, acco[n], 0, 0, 0);
        }
    }
    #pragma unroll
    for (int n = 0; n < 4; ++n)
        #pragma unroll
        for (int e = 0; e < 4; ++e)
            Oi[gbase + (size_t)(m0 + kb * 4 + e) * 1024 + n * 16 + lr] = (bf16_t)acco[n][e];
}

// ---------------- fused inter1 + intra2 (E from bf16 xb) ----------------
__global__ __launch_bounds__(256) void inter1_intra2_kernel(
    const bf16_t* __restrict__ Qr, const bf16_t* __restrict__ q2p,
    const bf16_t* __restrict__ k2p, const bf16_t* __restrict__ dT1,
    const bf16_t* __restrict__ Oi1, const bf16_t* __restrict__ xbin,
    bf16_t* __restrict__ O1g, bf16_t* __restrict__ dT2, bf16_t* __restrict__ Oi2)
{
    __shared__ __align__(16) bf16_t sQ  [64 * LPAD];
    __shared__ __align__(16) bf16_t sq2 [64 * LPAD];
    __shared__ __align__(16) bf16_t sK2 [64 * LPAD];
    __shared__ __align__(16) bf16_t sk2t[64 * LPAD];
    __shared__ __align__(16) bf16_t sEt [64 * LPAD];
    __shared__ __align__(16) bf16_t sP  [64 * LPAD];
    __shared__ __align__(16) bf16_t sT  [64 * LPAD];

    const int bid = blockIdx.x;
    const int c  = bid & (NC - 1);
    const int bh = bid >> 4;
    const int b = bh >> 4, h = bh & 15;
    const int tid = threadIdx.x;
    const size_t gbase = ((size_t)b * Lsz + (size_t)c * 64) * Dsz + h * Dh;

    #pragma unroll
    for (int it = 0; it < 2; ++it) {
        const int cc = tid + it * 256;
        const int j = cc >> 3;
        const int d0 = (cc & 7) * 8;
        const size_t g = gbase + (size_t)j * 1024 + d0;
        bf16x8 qv  = *reinterpret_cast<const bf16x8*>(&Qr[g]);
        bf16x8 q2v = *reinterpret_cast<const bf16x8*>(&q2p[g]);
        bf16x8 k2v = *reinterpret_cast<const bf16x8*>(&k2p[g]);
        *reinterpret_cast<bf16x8*>(&sQ [j * LPAD + d0]) = qv;
        *reinterpret_cast<bf16x8*>(&sq2[j * LPAD + d0]) = q2v;
        *reinterpret_cast<bf16x8*>(&sK2[j * LPAD + d0]) = k2v;
        #pragma unroll
        for (int i = 0; i < 8; ++i)
            sk2t[(d0 + i) * LPAD + j] = k2v[i];
    }
    {   // exclusive prefix of dT1 over chunks -> sT (S1^T bf16), f32 accumulate
        const bf16_t* tb = dT1 + (size_t)bh * NC * 4096 + tid * 16;
        float acc[16];
        #pragma unroll
        for (int k = 0; k < 16; ++k) acc[k] = 0.f;
        for (int cc = 0; cc < c; ++cc) {
            bf16x8 v0 = *reinterpret_cast<const bf16x8*>(&tb[(size_t)cc * 4096]);
            bf16x8 v1 = *reinterpret_cast<const bf16x8*>(&tb[(size_t)cc * 4096 + 8]);
            #pragma unroll
            for (int k = 0; k < 8; ++k) { acc[k] += (float)v0[k]; acc[8 + k] += (float)v1[k]; }
        }
        const int row = tid >> 2;
        const int c16 = (tid & 3) * 16;
        bf16x8 o0, o1v;
        #pragma unroll
        for (int k = 0; k < 8; ++k) { o0[k] = (bf16_t)acc[k]; o1v[k] = (bf16_t)acc[8 + k]; }
        *reinterpret_cast<bf16x8*>(&sT[row * LPAD + c16]) = o0;
        *reinterpret_cast<bf16x8*>(&sT[row * LPAD + c16 + 8]) = o1v;
    }
    __syncthreads();

    const int w = tid >> 6;
    const int lane = tid & 63;
    const int lr = lane & 15;
    const int kb = lane >> 4;
    const int m0 = w * 16;

    f32x4v acci[4], accp[4];
    #pragma unroll
    for (int n = 0; n < 4; ++n) { acci[n] = (f32x4v){0,0,0,0}; accp[n] = (f32x4v){0,0,0,0}; }
    #pragma unroll
    for (int kk = 0; kk < 2; ++kk) {
        const int c0 = kk * 32 + kb * 8;
        bf16x8 aq  = *reinterpret_cast<const bf16x8*>(&sQ [(m0 + lr) * LPAD + c0]);
        bf16x8 aq2 = *reinterpret_cast<const bf16x8*>(&sq2[(m0 + lr) * LPAD + c0]);
        #pragma unroll
        for (int n = 0; n < 4; ++n) {
            bf16x8 bs = *reinterpret_cast<const bf16x8*>(&sT [(n * 16 + lr) * LPAD + c0]);
            bf16x8 bk = *reinterpret_cast<const bf16x8*>(&sK2[(n * 16 + lr) * LPAD + c0]);
            acci[n] = __builtin_amdgcn_mfma_f32_16x16x32_bf16(aq,  bs, acci[n], 0, 0, 0);
            accp[n] = __builtin_amdgcn_mfma_f32_16x16x32_bf16(aq2, bk, accp[n], 0, 0, 0);
        }
    }
    #pragma unroll
    for (int n = 0; n < 4; ++n)
        #pragma unroll
        for (int e = 0; e < 4; ++e) {
            const int iLoc = m0 + kb * 4 + e;
            const int col = n * 16 + lr;
            const int lg = c * 64 + iLoc;
            const size_t idx = gbase + (size_t)iLoc * 1024 + col;
            const float o1 = acci[n][e] + (float)Oi1[idx];
            O1g[idx] = (bf16_t)o1;
            const float ev = (lg < Lsz - 1) ? ((float)xbin[idx + 1024] - o1) : 0.f;
            sEt[col * LPAD + iLoc] = (bf16_t)ev;
            sP[iLoc * LPAD + col] = (bf16_t)((col <= iLoc) ? accp[n][e] : 0.f);
        }
    __syncthreads();

    f32x4v acct[4], oi2[4];
    #pragma unroll
    for (int n = 0; n < 4; ++n) { acct[n] = (f32x4v){0,0,0,0}; oi2[n] = (f32x4v){0,0,0,0}; }
    #pragma unroll
    for (int kk = 0; kk < 2; ++kk) {
        const int c0 = kk * 32 + kb * 8;
        bf16x8 ae = *reinterpret_cast<const bf16x8*>(&sEt[(m0 + lr) * LPAD + c0]);
        bf16x8 ap = *reinterpret_cast<const bf16x8*>(&sP [(m0 + lr) * LPAD + c0]);
        #pragma unroll
        for (int n = 0; n < 4; ++n) {
            bf16x8 bt = *reinterpret_cast<const bf16x8*>(&sk2t[(n * 16 + lr) * LPAD + c0]);
            bf16x8 be = *reinterpret_cast<const bf16x8*>(&sEt [(n * 16 + lr) * LPAD + c0]);
            acct[n] = __builtin_amdgcn_mfma_f32_16x16x32_bf16(ae, bt, acct[n], 0, 0, 0);
            oi2[n]  = __builtin_amdgcn_mfma_f32_16x16x32_bf16(ap, be, oi2[n],  0, 0, 0);
        }
    }
    const size_t tbase = (size_t)bid * 4096;
    #pragma unroll
    for (int n = 0; n < 4; ++n)
        #pragma unroll
        for (int e = 0; e < 4; ++e) {
            const int r = m0 + kb * 4 + e;
            const int col = n * 16 + lr;
            dT2[tbase + (size_t)r * 64 + col] = (bf16_t)acct[n][e];
            Oi2[gbase + (size_t)r * 1024 + col] = (bf16_t)oi2[n][e];
        }
}

// ---------------- inter2: O2 = q2@S2 + Oi2; yb[l+1] = bf16(O1[l+1]+O2[l]) ----------------
__global__ __launch_bounds__(256) void inter2_kernel(
    const bf16_t* __restrict__ Ap, const bf16_t* __restrict__ dT,
    const bf16_t* __restrict__ Oi, const bf16_t* __restrict__ o1in,
    bf16_t* __restrict__ yb)
{
    __shared__ __align__(16) bf16_t sA[64 * LPAD];
    __shared__ __align__(16) bf16_t sT[64 * LPAD];

    const int bid = blockIdx.x;
    const int c  = bid & (NC - 1);
    const int bh = bid >> 4;
    const int b = bh >> 4, h = bh & 15;
    const int tid = threadIdx.x;
    const size_t gbase = ((size_t)b * Lsz + (size_t)c * 64) * Dsz + h * Dh;

    #pragma unroll
    for (int cc = tid; cc < 512; cc += 256) {
        const int j = cc >> 3;
        const int d0 = (cc & 7) * 8;
        bf16x8 av = *reinterpret_cast<const bf16x8*>(&Ap[gbase + (size_t)j * 1024 + d0]);
        *reinterpret_cast<bf16x8*>(&sA[j * LPAD + d0]) = av;
    }
    {
        const bf16_t* tb = dT + (size_t)bh * NC * 4096 + tid * 16;
        float acc[16];
        #pragma unroll
        for (int k = 0; k < 16; ++k) acc[k] = 0.f;
        for (int cc = 0; cc < c; ++cc) {
            bf16x8 v0 = *reinterpret_cast<const bf16x8*>(&tb[(size_t)cc * 4096]);
            bf16x8 v1 = *reinterpret_cast<const bf16x8*>(&tb[(size_t)cc * 4096 + 8]);
            #pragma unroll
            for (int k = 0; k < 8; ++k) { acc[k] += (float)v0[k]; acc[8 + k] += (float)v1[k]; }
        }
        const int row = tid >> 2;
        const int c16 = (tid & 3) * 16;
        bf16x8 o0, o1v;
        #pragma unroll
        for (int k = 0; k < 8; ++k) { o0[k] = (bf16_t)acc[k]; o1v[k] = (bf16_t)acc[8 + k]; }
        *reinterpret_cast<bf16x8*>(&sT[row * LPAD + c16]) = o0;
        *reinterpret_cast<bf16x8*>(&sT[row * LPAD + c16 + 8]) = o1v;
    }
    __syncthreads();

    const int w = tid >> 6;
    const int lane = tid & 63;
    const int lr = lane & 15;
    const int kb = lane >> 4;
    const int m0 = w * 16;

    f32x4v acc[4];
    #pragma unroll
    for (int n = 0; n < 4; ++n) acc[n] = (f32x4v){0,0,0,0};
    #pragma unroll
    for (int kk = 0; kk < 2; ++kk) {
        const int c0 = kk * 32 + kb * 8;
        bf16x8 a = *reinterpret_cast<const bf16x8*>(&sA[(m0 + lr) * LPAD + c0]);
        #pragma unroll
        for (int n = 0; n < 4; ++n) {
            bf16x8 bb = *reinterpret_cast<const bf16x8*>(&sT[(n * 16 + lr) * LPAD + c0]);
            acc[n] = __builtin_amdgcn_mfma_f32_16x16x32_bf16(a, bb, acc[n], 0, 0, 0);
        }
    }

    #pragma unroll
    for (int n = 0; n < 4; ++n)
        #pragma unroll
        for (int e = 0; e < 4; ++e) {
            const int iLoc = m0 + kb * 4 + e;
            const int lg = c * 64 + iLoc;
            const size_t idx = gbase + (size_t)iLoc * 1024 + n * 16 + lr;
            const float o2 = acc[n][e] + (float)Oi[idx];
            if (lg < Lsz - 1) yb[idx + 1024] = (bf16_t)((float)o1in[idx + 1024] + o2);
            if (lg == 0)      yb[idx] = o1in[idx];
        }
}

extern "C" void kernel_launch(void* const* d_in, const int* in_sizes, int n_in,
                              void* d_out, int out_size, void* d_ws, size_t ws_size,
                              hipStream_t stream) {
    const float* x   = (const float*)d_in[0];
    const float* Wq  = (const float*)d_in[1];
    const float* bq  = (const float*)d_in[2];
    const float* Wk1 = (const float*)d_in[3];
    const float* bk1 = (const float*)d_in[4];
    const float* Wv  = (const float*)d_in[5];
    const float* bv  = (const float*)d_in[6];
    const float* Wk2 = (const float*)d_in[7];
    const float* bk2 = (const float*)d_in[8];
    const float* Wp  = (const float*)d_in[9];
    const float* bp  = (const float*)d_in[10];
    float* out = (float*)d_out;
    float* ws  = (float*)d_ws;

    const size_t mat = (size_t)Mtot * Dsz;     // 2M elements
    bf16_t* O1  = (bf16_t*)ws;                  // bf16               [0, 1M)
    bf16_t* Oib = (bf16_t*)(ws + 2 * mat);      // bf16               [2M, 3M)
    bf16_t* dT1 = (bf16_t*)(ws + 3 * mat);      // bf16               [3M, 4M)
    bf16_t* dT2 = (bf16_t*)(ws + 4 * mat);      // bf16               [4M, 5M)
    bf16_t* xb  = (bf16_t*)(ws + 5 * mat);      // bf16               [5M, 6M)
    bf16_t* Wt  = (bf16_t*)(ws + 6 * mat);      // bf16 5M            [6M, 8.5M)
    float*  bb  = ws + 8 * mat + mat / 2;       // 8.5M
    bf16_t* Qr  = (bf16_t*)(bb);                // [8.5M, 9.5M)
    bf16_t* q2  = (bf16_t*)(bb + mat / 2);      // [9.5M, 10.5M)
    bf16_t* Kb  = (bf16_t*)(bb + mat);          // [10.5M, 11.5M)
    bf16_t* Vb  = (bf16_t*)(bb + 3 * mat / 2);  // [11.5M, 12.5M)
    bf16_t* k2  = (bf16_t*)(bb + 2 * mat);      // [12.5M, 13.5M)
    bf16_t* yb  = Qr;                           // Qr dead after inter1_intra2

    dim3 block(256);

    prep_kernel<<<dim3(16, 16, 6), block, 0, stream>>>(x, xb, Wq, Wk1, Wv, Wk2, Wp, Wt);

    bgemm_kernel<0><<<dim3(256), dim3(512), 0, stream>>>(
        xb, Wt, bq, bk1, bv, bk2, Qr, q2, Kb, Vb, k2, nullptr);

    chunk_intra_kernel<<<dim3(512), block, 0, stream>>>(Qr, Kb, Vb, Oib, dT1);
    inter1_intra2_kernel<<<dim3(512), block, 0, stream>>>(Qr, q2, k2, dT1, Oib, xb, O1, dT2, Oib);
    inter2_kernel<<<dim3(512), block, 0, stream>>>(q2, dT2, Oib, O1, yb);

    bgemm_kernel<1><<<dim3(512), block, 0, stream>>>(
        yb, Wt + 4 * 1048576, bp, nullptr, nullptr, nullptr,
        nullptr, nullptr, nullptr, nullptr, nullptr, out);
}